// Round 3
// baseline (1402.118 us; speedup 1.0000x reference)
//
#include <hip/hip_runtime.h>
#include <cstdint>
#include <cstddef>

typedef __attribute__((ext_vector_type(8))) short bf16x8;
typedef __attribute__((ext_vector_type(4))) short bf16x4v;
typedef __attribute__((ext_vector_type(4))) float f32x4;

__device__ inline short f2bf(float f) {
  union { float f; unsigned u; } c; c.f = f;
  unsigned u = c.u;
  unsigned r = (u + 0x7fffu + ((u >> 16) & 1u)) >> 16;
  return (short)r;
}
__device__ inline float swish_f(float v) { return v / (1.f + __expf(-v)); }

__device__ inline void gld_lds16(const void* g, void* l) {
  __builtin_amdgcn_global_load_lds((const __attribute__((address_space(1))) void*)g,
                                   (__attribute__((address_space(3))) void*)l, 16, 0, 0);
}

// Counted-vmcnt acquire: certify all but the newest VM loads, then barrier.
#define ACQ(VM) do {                                                     \
    asm volatile("s_waitcnt vmcnt(" VM ")" ::: "memory");                \
    __builtin_amdgcn_s_barrier();                                        \
    asm volatile("" ::: "memory");                                       \
  } while (0)
// Release barrier: reads of the outgoing buffer retired before this point.
#define REL() do {                                                       \
    asm volatile("" ::: "memory");                                       \
    __builtin_amdgcn_s_barrier();                                        \
  } while (0)

// ------------------------------------------------------------------
// s1 = embed @ d1_w + d1_b  (4x64);  s2 = context @ d2_w + d2_b (4x128)
__global__ __launch_bounds__(256) void scales_kernel(
    const float* __restrict__ embed, const float* __restrict__ context,
    const float* __restrict__ d1w, const float* __restrict__ d1b,
    const float* __restrict__ d2w, const float* __restrict__ d2b,
    float* __restrict__ s1, float* __restrict__ s2) {
  int tid = blockIdx.x * 256 + threadIdx.x;
  if (tid < 256) {
    int b = tid >> 6, c = tid & 63;
    float acc = d1b[c];
    for (int e = 0; e < 256; ++e) acc += embed[b * 256 + e] * d1w[e * 64 + c];
    s1[tid] = acc;
  } else if (tid < 768) {
    int o = tid - 256;
    int b = o >> 7, c = o & 127;
    float acc = d2b[c];
    for (int e = 0; e < 256; ++e) acc += context[b * 256 + e] * d2w[e * 128 + c];
    s2[o] = acc;
  }
}

// ------------------------------------------------------------------
// Weight repack: w[co][ci][kz][ky][kx] fp32 -> wt[tap][co][ci] bf16
__global__ __launch_bounds__(256) void prep_w_kernel(
    const float* __restrict__ w20, const float* __restrict__ w21,
    const float* __restrict__ wdn, const float* __restrict__ rsw,
    short* __restrict__ wt20, short* __restrict__ wt21,
    short* __restrict__ wtdn, short* __restrict__ rw) {
  for (int o = blockIdx.x * 256 + threadIdx.x; o < 1114112; o += gridDim.x * 256) {
    if (o < 221184) {                       // wt20: 27*128*64
      int t = o >> 13, rem = o & 8191, co = rem >> 6, ci = rem & 63;
      wt20[o] = f2bf(w20[(co * 64 + ci) * 27 + t]);
    } else if (o < 663552) {                // wt21: 27*128*128
      int p = o - 221184;
      int t = p >> 14, rem = p & 16383, co = rem >> 7, ci = rem & 127;
      wt21[p] = f2bf(w21[(co * 128 + ci) * 27 + t]);
    } else if (o < 1105920) {               // wtdn: 27*128*128
      int p = o - 663552;
      int t = p >> 14, rem = p & 16383, co = rem >> 7, ci = rem & 127;
      wtdn[p] = f2bf(wdn[(co * 128 + ci) * 27 + t]);
    } else {                                // rw: 128*64 (1x1x1, same order)
      int p = o - 1105920;
      rw[p] = f2bf(rsw[p]);
    }
  }
}

// ------------------------------------------------------------------
// h1[b][z][y][x][ci] bf16 = swish(x + s1[b][ci]); channels-last via LDS transpose
__global__ __launch_bounds__(256) void prep_h1_kernel(
    const float* __restrict__ xin, const float* __restrict__ s1,
    short* __restrict__ h1) {
  __shared__ __align__(16) short sm[128 * 72];
  const int tid = threadIdx.x;
  const int gid = blockIdx.x;               // = b*1024 + z*128 + y
  const int y = gid & 127, z = (gid >> 7) & 7, b = gid >> 10;
  const float* xbase = xin + (size_t)b * 8388608 + (size_t)z * 16384 + (size_t)y * 128;
#pragma unroll
  for (int i = 0; i < 8; ++i) {             // 2048 float4
    int e = i * 256 + tid;
    int ci = e >> 5, x4 = e & 31;
    float4 v = *(const float4*)(xbase + (size_t)ci * 131072 + x4 * 4);
    float s = s1[b * 64 + ci];
    sm[(x4 * 4 + 0) * 72 + ci] = f2bf(swish_f(v.x + s));
    sm[(x4 * 4 + 1) * 72 + ci] = f2bf(swish_f(v.y + s));
    sm[(x4 * 4 + 2) * 72 + ci] = f2bf(swish_f(v.z + s));
    sm[(x4 * 4 + 3) * 72 + ci] = f2bf(swish_f(v.w + s));
  }
  __syncthreads();
  short* orow = h1 + (size_t)gid * 8192;
#pragma unroll
  for (int i = 0; i < 4; ++i) {             // 1024 vec8
    int e = i * 256 + tid;
    int xx = e >> 3, c8 = e & 7;
    *(bf16x8*)(orow + e * 8) = *(const bf16x8*)(&sm[xx * 72 + c8 * 8]);
  }
}

// ------------------------------------------------------------------
// conv20: h2 = swish(conv3d(h1, w20) + b20) * s2   (Cin=64 -> Cout=128), bf16 out
// Cross-step bb prefetch: inbuf is stable within a (kz,ky) group, so bb for
// step s+1 is read during step s's MFMA phase; only af waits on the ACQ.
__global__ __launch_bounds__(256, 3) void conv20_kernel(
    const short* __restrict__ h1, const short* __restrict__ wt,
    const float* __restrict__ b20, const float* __restrict__ s2,
    short* __restrict__ h2) {
  __shared__ __align__(16) short sm[24704];   // inbuf 8320 + wbuf 2*8192
  const int tid = threadIdx.x;
  const int bi = blockIdx.x;
  const int xcd = bi & 7, slot = bi >> 3;
  const int yo = slot & 15, z = (slot >> 4) & 7, b = slot >> 7;
  const int y = xcd * 16 + yo;
  const int gid = b * 1024 + z * 128 + y;
  const int lane = tid & 63, wave = tid >> 6;
  const int wm = wave >> 1, wn = wave & 1;
  const int q = lane >> 4, n0 = lane & 15;
  const bf16x8 zz = {0, 0, 0, 0, 0, 0, 0, 0};
  short* inbuf = sm;                          // [130 x][64 ci], 8-unit xor swizzle
  f32x4 acc[4][4];
#pragma unroll
  for (int i = 0; i < 4; ++i)
#pragma unroll
    for (int j = 0; j < 4; ++j) acc[i][j] = (f32x4){0.f, 0.f, 0.f, 0.f};

  auto wstage = [&](int s) {                  // tap s -> wbuf[s&1]; [co 128][8 units, u^co swz]
    const short* src = wt + (s << 13);
    short* dst = sm + 8320 + ((s & 1) << 13);
    int r = lane >> 3, ss = lane & 7;
#pragma unroll
    for (int i = 0; i < 4; ++i) {
      int c = wave * 4 + i;
      gld_lds16(src + ((c * 8 + r) << 6) + ((ss ^ r) << 3), dst + (c << 9));
    }
  };
  auto instage = [&](int it) {                // row (kz,ky)=it -> inbuf rows 1..128
    int kz = it / 3, ky = it - kz * 3;
    int zi = z + kz - 1, yi = y + ky - 1;
    if (zi >= 0 && zi < 8 && yi >= 0 && yi < 128) {
      const short* row = h1 + ((size_t)(b * 1024 + zi * 128 + yi) << 13);
#pragma unroll
      for (int i = 0; i < 4; ++i) {
        int x0 = 1 + 8 * (wave * 4 + i);
        int x = x0 + (lane >> 3);
        int c8 = (lane & 7) ^ (x & 7);
        gld_lds16(row + ((x - 1) << 6) + (c8 << 3), inbuf + (x0 << 6));
      }
    } else {
#pragma unroll
      for (int i = 0; i < 4; ++i)
        *(bf16x8*)(&inbuf[64 + (i * 256 + tid) * 8]) = zz;
      asm volatile("s_waitcnt lgkmcnt(0)" ::: "memory");
    }
  };
  auto rd_af = [&](int par, bf16x8 (&af)[2][4]) {
    const short* w = sm + 8320 + (par << 13);
#pragma unroll
    for (int ch = 0; ch < 2; ++ch)
#pragma unroll
      for (int i = 0; i < 4; ++i)
        af[ch][i] = *(const bf16x8*)(&w[(wm * 64 + i * 16 + n0) * 64 + (((ch * 4 + q) ^ (n0 & 7)) << 3)]);
  };
  auto rd_bb = [&](int kx, bf16x8 (&bb)[2][4]) {
#pragma unroll
    for (int ch = 0; ch < 2; ++ch)
#pragma unroll
      for (int j = 0; j < 4; ++j) {
        int xx = wn * 64 + j * 16 + n0 + kx;
        bb[ch][j] = *(const bf16x8*)(&inbuf[xx * 64 + (((ch * 4 + q) ^ (xx & 7)) << 3)]);
      }
  };
  auto domfma = [&](bf16x8 (&af)[2][4], bf16x8 (&bb)[2][4]) {
    __builtin_amdgcn_s_setprio(1);
#pragma unroll
    for (int ch = 0; ch < 2; ++ch)
#pragma unroll
      for (int i = 0; i < 4; ++i)
#pragma unroll
        for (int j = 0; j < 4; ++j)
          acc[i][j] = __builtin_amdgcn_mfma_f32_16x16x32_bf16(af[ch][i], bb[ch][j], acc[i][j], 0, 0, 0);
    __builtin_amdgcn_s_setprio(0);
  };

  if (tid < 16) {                             // halo rows 0,129 zero (persist)
    int hf = tid >> 3, u = tid & 7;
    *(bf16x8*)(&inbuf[(hf ? 129 : 0) * 64 + u * 8]) = zz;
  }
  wstage(0);
  instage(0);
  __syncthreads();                            // prologue: one full drain (once)

  bf16x8 af[2][4], bbA[2][4], bbB[2][4];
  for (int g = 0; g < 8; ++g) {               // groups of 3 steps (one (kz,ky) row)
#pragma unroll
    for (int u = 0; u < 3; ++u) {             // u == kx, compile-time
      const int s = g * 3 + u;
      wstage(s + 1);
      ACQ("4");                               // certify wstage(s) [+instage at u==0]
      rd_af(s & 1, af);
      if (u == 0) rd_bb(0, bbA);              // fresh inbuf: read own bb
      if (u == 0) rd_bb(1, bbB);              // prefetch next (hidden under MFMA)
      if (u == 1) rd_bb(2, bbA);
      domfma(af, (u & 1) ? bbB : bbA);
      REL();
      if (u == 2) instage(g + 1);             // in flight; certified by next ACQ
    }
  }
  {                                           // tail group g==8: s=24,25,26
    wstage(25); ACQ("4"); rd_af(0, af);
    rd_bb(0, bbA); rd_bb(1, bbB);
    domfma(af, bbA); REL();
    wstage(26); ACQ("4"); rd_af(1, af);
    rd_bb(2, bbA);
    domfma(af, bbB); REL();
    ACQ("0"); rd_af(0, af);
    domfma(af, bbA); REL();
  }
  // epilogue: bias + swish + s2, transpose through LDS, contiguous bf16 row out
#pragma unroll
  for (int i = 0; i < 4; ++i) {
    const int mb = wm * 64 + i * 16 + q * 4;
    const float4 bias = *(const float4*)(b20 + mb);
    const float4 sc = *(const float4*)(s2 + b * 128 + mb);
#pragma unroll
    for (int j = 0; j < 4; ++j) {
      const int n = wn * 64 + j * 16 + n0;
      bf16x4v pk;
      pk.x = f2bf(swish_f(acc[i][j][0] + bias.x) * sc.x);
      pk.y = f2bf(swish_f(acc[i][j][1] + bias.y) * sc.y);
      pk.z = f2bf(swish_f(acc[i][j][2] + bias.z) * sc.z);
      pk.w = f2bf(swish_f(acc[i][j][3] + bias.w) * sc.w);
      *(bf16x4v*)(&sm[n * 136 + mb]) = pk;
    }
  }
  __syncthreads();
  short* orow = h2 + (size_t)gid * 16384;
#pragma unroll
  for (int i = 0; i < 8; ++i) {               // 2048 vec8
    int e = i * 256 + tid;
    int xx = e >> 4, c8 = e & 15;
    *(bf16x8*)(orow + e * 8) = *(const bf16x8*)(&sm[xx * 136 + c8 * 8]);
  }
}

// ------------------------------------------------------------------
// conv21: h3 = swish(conv3d(h2, w21) + conv1x1(x, res_w) + res_b)  (128->128), bf16
// Cross-step bb prefetch (period-6 groups); af waits on ACQ, bb hides under MFMA.
__global__ __launch_bounds__(256, 2) void conv21_kernel(
    const short* __restrict__ h2, const short* __restrict__ wt,
    const float* __restrict__ xin, const short* __restrict__ rw,
    const float* __restrict__ res_b, short* __restrict__ h3) {
  __shared__ __align__(16) short sm[33024];   // inbuf 16640 + wbuf 2*8192
  const int tid = threadIdx.x;
  const int bi = blockIdx.x;
  const int xcd = bi & 7, slot = bi >> 3;
  const int yo = slot & 15, z = (slot >> 4) & 7, b = slot >> 7;
  const int y = xcd * 16 + yo;
  const int gid = b * 1024 + z * 128 + y;
  const int lane = tid & 63, wave = tid >> 6;
  const int wm = wave >> 1, wn = wave & 1;
  const int q = lane >> 4, n0 = lane & 15;
  const bf16x8 zz = {0, 0, 0, 0, 0, 0, 0, 0};
  short* inbuf = sm;                          // [130 x][128 ci], 16-unit xor swizzle
  f32x4 acc[4][4];
#pragma unroll
  for (int i = 0; i < 4; ++i)
#pragma unroll
    for (int j = 0; j < 4; ++j) acc[i][j] = (f32x4){0.f, 0.f, 0.f, 0.f};

  auto wstage = [&](int s) {                  // half-tap s -> wbuf[s&1]; [co 128][8 units, u^co]
    int it6 = s / 6, sub = s - it6 * 6, kx = sub >> 1, ch2 = sub & 1;
    const short* src = wt + (((it6 * 3 + kx) << 14) + (ch2 << 6));
    short* dst = sm + 16640 + ((s & 1) << 13);
    int r = lane >> 3, ss = lane & 7;
#pragma unroll
    for (int i = 0; i < 4; ++i) {
      int c = wave * 4 + i;
      gld_lds16(src + ((c * 8 + r) << 7) + ((ss ^ r) << 3), dst + (c << 9));
    }
  };
  auto instage = [&](int it) {
    int kz = it / 3, ky = it - kz * 3;
    int zi = z + kz - 1, yi = y + ky - 1;
    if (zi >= 0 && zi < 8 && yi >= 0 && yi < 128) {
      const short* row = h2 + ((size_t)(b * 1024 + zi * 128 + yi) << 14);
#pragma unroll
      for (int i = 0; i < 8; ++i) {
        int x0 = 1 + 4 * (wave * 8 + i);
        int x = x0 + (lane >> 4);
        int c8 = (lane & 15) ^ (x & 15);
        gld_lds16(row + ((x - 1) << 7) + (c8 << 3), inbuf + (x0 << 7));
      }
    } else {
#pragma unroll
      for (int i = 0; i < 8; ++i)
        *(bf16x8*)(&inbuf[128 + (i * 256 + tid) * 8]) = zz;
      asm volatile("s_waitcnt lgkmcnt(0)" ::: "memory");
    }
  };
  auto rd_af = [&](int par, bf16x8 (&af)[2][4]) {
    const short* w = sm + 16640 + (par << 13);
#pragma unroll
    for (int chL = 0; chL < 2; ++chL)
#pragma unroll
      for (int i = 0; i < 4; ++i)
        af[chL][i] = *(const bf16x8*)(&w[(wm * 64 + i * 16 + n0) * 64 + (((chL * 4 + q) ^ (n0 & 7)) << 3)]);
  };
  auto rd_bb = [&](int kx, int ch2, bf16x8 (&bb)[2][4]) {
#pragma unroll
    for (int chL = 0; chL < 2; ++chL) {
      const int ch = ch2 * 2 + chL;
#pragma unroll
      for (int j = 0; j < 4; ++j) {
        int xx = wn * 64 + j * 16 + n0 + kx;
        bb[chL][j] = *(const bf16x8*)(&inbuf[(xx << 7) + (((ch * 4 + q) ^ (xx & 15)) << 3)]);
      }
    }
  };
  auto domfma = [&](bf16x8 (&af)[2][4], bf16x8 (&bb)[2][4]) {
    __builtin_amdgcn_s_setprio(1);
#pragma unroll
    for (int chL = 0; chL < 2; ++chL)
#pragma unroll
      for (int i = 0; i < 4; ++i)
#pragma unroll
        for (int j = 0; j < 4; ++j)
          acc[i][j] = __builtin_amdgcn_mfma_f32_16x16x32_bf16(af[chL][i], bb[chL][j], acc[i][j], 0, 0, 0);
    __builtin_amdgcn_s_setprio(0);
  };

  if (tid < 32) {                             // halo rows 0,129 zero (persist)
    int hf = tid >> 4, u = tid & 15;
    *(bf16x8*)(&inbuf[(hf ? 129 : 0) * 128 + u * 8]) = zz;
  }
  wstage(0);
  instage(0);
  __syncthreads();                            // prologue: one full drain (once)

  bf16x8 af[2][4], bbA[2][4], bbB[2][4];
  float4 xv[8];
  for (int g = 0; g < 8; ++g) {               // groups of 6 steps (one (kz,ky) row)
#pragma unroll
    for (int u = 0; u < 6; ++u) {             // u = sub, compile-time
      const int s = g * 6 + u;
      wstage(s + 1);
      ACQ("4");
      rd_af(u & 1, af);                       // s&1 == u&1 (period 6 even)
      if (u == 0) rd_bb(0, 0, bbA);           // fresh inbuf: read own bb
      if (u < 5) rd_bb((u + 1) >> 1, (u + 1) & 1, (u & 1) ? bbA : bbB); // prefetch
      domfma(af, (u & 1) ? bbB : bbA);
      REL();
      if (u == 5) instage(g + 1);             // in flight; certified by next ACQ
    }
  }
  {                                           // tail group g==8: s=48..53
    wstage(49); ACQ("4"); rd_af(0, af);
    rd_bb(0, 0, bbA); rd_bb(0, 1, bbB);
    domfma(af, bbA); REL();
    wstage(50); ACQ("4"); rd_af(1, af);
    rd_bb(1, 0, bbA);
    domfma(af, bbB); REL();
    wstage(51); ACQ("4"); rd_af(0, af);
    rd_bb(1, 1, bbB);
    domfma(af, bbA); REL();
    wstage(52); ACQ("4");
    {                                         // s==51: prefetch fp32 res row to regs
      const float* xb = xin + (size_t)b * 8388608 + (size_t)z * 16384 + (size_t)y * 128;
#pragma unroll
      for (int i = 0; i < 8; ++i) {
        int e = i * 256 + tid;
        int ci = e >> 5, x4 = e & 31;
        xv[i] = *(const float4*)(xb + (size_t)ci * 131072 + x4 * 4);
      }
    }
    rd_af(1, af);
    rd_bb(2, 0, bbA);
    domfma(af, bbB); REL();
    wstage(53); ACQ("12");                    // certify w52; xv(8)+w53(4) in flight
    rd_af(0, af);
    rd_bb(2, 1, bbB);
    domfma(af, bbA); REL();
    ACQ("0");                                 // certify w53
    rd_af(1, af);
    domfma(af, bbB); REL();
  }
  // res 1x1 tap: write x row (bf16, 64-ci swizzle incl. (xx>>3) bit) into free wbuf
  short* rbuf = sm + 16640;                   // s=53 read parity 1; buf 0 free
  {
#pragma unroll
    for (int i = 0; i < 8; ++i) {
      int e = i * 256 + tid;
      int ci = e >> 5, x4 = e & 31;
      int u0 = ci >> 3, cl = ci & 7;
#pragma unroll
      for (int k = 0; k < 4; ++k) {
        int xx = x4 * 4 + k;
        float fv = (k == 0) ? xv[i].x : (k == 1) ? xv[i].y : (k == 2) ? xv[i].z : xv[i].w;
        rbuf[xx * 64 + ((u0 ^ (xx & 7) ^ ((xx >> 3) & 7)) << 3) + cl] = f2bf(fv);
      }
    }
  }
  __syncthreads();
#pragma unroll
  for (int ch = 0; ch < 2; ++ch) {
    bf16x8 raf[4], rbb[4];
#pragma unroll
    for (int i = 0; i < 4; ++i)
      raf[i] = *(const bf16x8*)(rw + (wm * 64 + i * 16 + n0) * 64 + ch * 32 + q * 8);
#pragma unroll
    for (int j = 0; j < 4; ++j) {
      int xx = wn * 64 + j * 16 + n0;
      rbb[j] = *(const bf16x8*)(&rbuf[xx * 64 + (((ch * 4 + q) ^ (xx & 7) ^ ((xx >> 3) & 7)) << 3)]);
    }
#pragma unroll
    for (int i = 0; i < 4; ++i)
#pragma unroll
      for (int j = 0; j < 4; ++j)
        acc[i][j] = __builtin_amdgcn_mfma_f32_16x16x32_bf16(raf[i], rbb[j], acc[i][j], 0, 0, 0);
  }
  __syncthreads();
  // epilogue: + res_b, swish, bf16 out (channels-last)
#pragma unroll
  for (int i = 0; i < 4; ++i) {
    const int mb = wm * 64 + i * 16 + q * 4;
    const float4 bias = *(const float4*)(res_b + mb);
#pragma unroll
    for (int j = 0; j < 4; ++j) {
      const int n = wn * 64 + j * 16 + n0;
      bf16x4v pk;
      pk.x = f2bf(swish_f(acc[i][j][0] + bias.x));
      pk.y = f2bf(swish_f(acc[i][j][1] + bias.y));
      pk.z = f2bf(swish_f(acc[i][j][2] + bias.z));
      pk.w = f2bf(swish_f(acc[i][j][3] + bias.w));
      *(bf16x4v*)(&sm[n * 136 + mb]) = pk;
    }
  }
  __syncthreads();
  short* orow = h3 + (size_t)gid * 16384;
#pragma unroll
  for (int i = 0; i < 8; ++i) {
    int e = i * 256 + tid;
    int xx = e >> 4, c8 = e & 15;
    *(bf16x8*)(orow + e * 8) = *(const bf16x8*)(&sm[xx * 136 + c8 * 8]);
  }
}

// ------------------------------------------------------------------
// down: out = conv3d(h3, down_w, stride (1,2,2), pad z only) + down_b, fp32 NCDHW
__global__ __launch_bounds__(256, 2) void down_kernel(
    const short* __restrict__ h3, const short* __restrict__ wt,
    const float* __restrict__ dnb, float* __restrict__ out) {
  __shared__ __align__(16) short sm[33024];   // inbuf 16640 + wbuf 2*8192
  const int tid = threadIdx.x;
  const int bi = blockIdx.x;                  // 4*8*63 = 2016
  const int o = (bi & 7) * 252 + (bi >> 3);
  const int yo = o % 63;
  const int zb = o / 63;
  const int z = zb & 7, b = zb >> 3;
  const int lane = tid & 63, wave = tid >> 6;
  const int wm = wave >> 1, wn = wave & 1;
  const int q = lane >> 4, n0 = lane & 15;
  const bf16x8 zz = {0, 0, 0, 0, 0, 0, 0, 0};
  short* inbuf = sm;                          // [130 x][128 ci], rows 0..127 data
  f32x4 acc[4][2];
#pragma unroll
  for (int i = 0; i < 4; ++i)
#pragma unroll
    for (int j = 0; j < 2; ++j) acc[i][j] = (f32x4){0.f, 0.f, 0.f, 0.f};

  auto wstage = [&](int s) {
    int it6 = s / 6, sub = s - it6 * 6, kx = sub >> 1, ch2 = sub & 1;
    const short* src = wt + (((it6 * 3 + kx) << 14) + (ch2 << 6));
    short* dst = sm + 16640 + ((s & 1) << 13);
    int r = lane >> 3, ss = lane & 7;
#pragma unroll
    for (int i = 0; i < 4; ++i) {
      int c = wave * 4 + i;
      gld_lds16(src + ((c * 8 + r) << 7) + ((ss ^ r) << 3), dst + (c << 9));
    }
  };
  auto instage = [&](int it) {
    int kz = it / 3, ky = it - kz * 3;
    int zi = z + kz - 1;
    int yi = 2 * yo + ky;                     // always in range
    if (zi >= 0 && zi < 8) {
      const short* row = h3 + ((size_t)(b * 1024 + zi * 128 + yi) << 14);
#pragma unroll
      for (int i = 0; i < 8; ++i) {
        int x0 = 4 * (wave * 8 + i);          // no x shift
        int x = x0 + (lane >> 4);
        int c8 = (lane & 15) ^ (x & 15);
        gld_lds16(row + (x << 7) + (c8 << 3), inbuf + (x0 << 7));
      }
    } else {
#pragma unroll
      for (int i = 0; i < 8; ++i)
        *(bf16x8*)(&inbuf[(i * 256 + tid) * 8]) = zz;
      asm volatile("s_waitcnt lgkmcnt(0)" ::: "memory");
    }
  };
  auto rd_af = [&](int par, bf16x8 (&af)[2][4]) {
    const short* w = sm + 16640 + (par << 13);
#pragma unroll
    for (int chL = 0; chL < 2; ++chL)
#pragma unroll
      for (int i = 0; i < 4; ++i)
        af[chL][i] = *(const bf16x8*)(&w[(wm * 64 + i * 16 + n0) * 64 + (((chL * 4 + q) ^ (n0 & 7)) << 3)]);
  };
  auto rd_bb = [&](int kx, int ch2, bf16x8 (&bb)[2][2]) {
#pragma unroll
    for (int chL = 0; chL < 2; ++chL) {
      const int ch = ch2 * 2 + chL;
#pragma unroll
      for (int j = 0; j < 2; ++j) {
        int xp = 2 * (wn * 32 + j * 16 + n0) + kx;
        bb[chL][j] = *(const bf16x8*)(&inbuf[(xp << 7) + (((ch * 4 + q) ^ (xp & 15)) << 3)]);
      }
    }
  };
  auto domfma = [&](bf16x8 (&af)[2][4], bf16x8 (&bb)[2][2]) {
    __builtin_amdgcn_s_setprio(1);
#pragma unroll
    for (int chL = 0; chL < 2; ++chL)
#pragma unroll
      for (int i = 0; i < 4; ++i)
#pragma unroll
        for (int j = 0; j < 2; ++j)
          acc[i][j] = __builtin_amdgcn_mfma_f32_16x16x32_bf16(af[chL][i], bb[chL][j], acc[i][j], 0, 0, 0);
    __builtin_amdgcn_s_setprio(0);
  };

  if (tid < 32) {                             // rows 128,129 zero (dead n=63 lanes)
    int hf = tid >> 4, u = tid & 15;
    *(bf16x8*)(&inbuf[(128 + hf) * 128 + u * 8]) = zz;
  }
  wstage(0);
  instage(0);
  __syncthreads();                            // prologue: one full drain (once)

  bf16x8 af[2][4], bbA[2][2], bbB[2][2];
  for (int g = 0; g < 8; ++g) {
#pragma unroll
    for (int u = 0; u < 6; ++u) {
      const int s = g * 6 + u;
      wstage(s + 1);
      ACQ("4");
      rd_af(u & 1, af);
      if (u == 0) rd_bb(0, 0, bbA);
      if (u < 5) rd_bb((u + 1) >> 1, (u + 1) & 1, (u & 1) ? bbA : bbB);
      domfma(af, (u & 1) ? bbB : bbA);
      REL();
      if (u == 5) instage(g + 1);
    }
  }
  {                                           // tail group g==8: s=48..53
    wstage(49); ACQ("4"); rd_af(0, af);
    rd_bb(0, 0, bbA); rd_bb(0, 1, bbB);
    domfma(af, bbA); REL();
    wstage(50); ACQ("4"); rd_af(1, af);
    rd_bb(1, 0, bbA);
    domfma(af, bbB); REL();
    wstage(51); ACQ("4"); rd_af(0, af);
    rd_bb(1, 1, bbB);
    domfma(af, bbA); REL();
    wstage(52); ACQ("4"); rd_af(1, af);
    rd_bb(2, 0, bbA);
    domfma(af, bbB); REL();
    wstage(53); ACQ("4"); rd_af(0, af);
    rd_bb(2, 1, bbB);
    domfma(af, bbA); REL();
    ACQ("0"); rd_af(1, af);
    domfma(af, bbB); REL();
  }
  // epilogue: + down_b, fp32 transpose in LDS (stride 133: conflict-free), NCDHW out
  float* fsm = (float*)sm;
#pragma unroll
  for (int i = 0; i < 4; ++i) {
    const int mb = wm * 64 + i * 16 + q * 4;
    const float4 bias = *(const float4*)(dnb + mb);
#pragma unroll
    for (int j = 0; j < 2; ++j) {
      const int n = wn * 32 + j * 16 + n0;
      f32x4 v;
      v[0] = acc[i][j][0] + bias.x;
      v[1] = acc[i][j][1] + bias.y;
      v[2] = acc[i][j][2] + bias.z;
      v[3] = acc[i][j][3] + bias.w;
      *(f32x4*)(&fsm[n * 133 + mb]) = v;
    }
  }
  __syncthreads();
#pragma unroll
  for (int it = 0; it < 32; ++it) {           // 128 co x 64 lanes (63 valid)
    int idx = it * 256 + tid;
    int co = idx >> 6, xl = idx & 63;
    if (xl < 63)
      out[((size_t)(b * 128 + co) * 8 + z) * 3969 + yo * 63 + xl] = fsm[xl * 133 + co];
  }
}

// ------------------------------------------------------------------
extern "C" void kernel_launch(void* const* d_in, const int* in_sizes, int n_in,
                              void* d_out, int out_size, void* d_ws, size_t ws_size,
                              hipStream_t stream) {
  const float* x       = (const float*)d_in[0];
  const float* embed   = (const float*)d_in[1];
  const float* context = (const float*)d_in[2];
  const float* w20     = (const float*)d_in[3];
  const float* b20     = (const float*)d_in[4];
  const float* w21     = (const float*)d_in[5];
  const float* d1w     = (const float*)d_in[6];
  const float* d1b     = (const float*)d_in[7];
  const float* d2w     = (const float*)d_in[8];
  const float* d2b     = (const float*)d_in[9];
  const float* resw    = (const float*)d_in[10];
  const float* resb    = (const float*)d_in[11];
  const float* dnw     = (const float*)d_in[12];
  const float* dnb     = (const float*)d_in[13];
  float* out = (float*)d_out;
  char* ws = (char*)d_ws;
  float* s1   = (float*)(ws + 0);          // 1 KB
  float* s2   = (float*)(ws + 1024);       // 2 KB
  short* wt20 = (short*)(ws + 4096);       // 432 KB
  short* wt21 = (short*)(ws + 446464);     // 864 KB
  short* wtdn = (short*)(ws + 1331200);    // 864 KB
  short* rw   = (short*)(ws + 2215936);    // 16 KB
  short* h1   = (short*)(ws + 2232320);    // 64 MB  [b][z][y][x][ci=64] bf16
  short* h2   = (short*)(ws + 69341184);   // 128 MB [b][z][y][x][ci=128] bf16
  short* h3   = (short*)(ws + 203558912);  // 128 MB [b][z][y][x][ci=128] bf16

  scales_kernel<<<3, 256, 0, stream>>>(embed, context, d1w, d1b, d2w, d2b, s1, s2);
  prep_w_kernel<<<1088, 256, 0, stream>>>(w20, w21, dnw, resw, wt20, wt21, wtdn, rw);
  prep_h1_kernel<<<4096, 256, 0, stream>>>(x, s1, h1);
  conv20_kernel<<<4096, 256, 0, stream>>>(h1, wt20, b20, s2, h2);
  conv21_kernel<<<4096, 256, 0, stream>>>(h2, wt21, x, rw, resb, h3);
  down_kernel<<<2016, 256, 0, stream>>>(h3, wtdn, dnb, out);
}

// Round 4
// 1268.127 us; speedup vs baseline: 1.1057x; 1.1057x over previous
//
#include <hip/hip_runtime.h>
#include <cstdint>
#include <cstddef>

typedef __attribute__((ext_vector_type(8))) short bf16x8;
typedef __attribute__((ext_vector_type(4))) short bf16x4v;
typedef __attribute__((ext_vector_type(4))) float f32x4;

__device__ inline short f2bf(float f) {
  union { float f; unsigned u; } c; c.f = f;
  unsigned u = c.u;
  unsigned r = (u + 0x7fffu + ((u >> 16) & 1u)) >> 16;
  return (short)r;
}
__device__ inline float swish_f(float v) { return v / (1.f + __expf(-v)); }

__device__ inline void gld_lds16(const void* g, void* l) {
  __builtin_amdgcn_global_load_lds((const __attribute__((address_space(1))) void*)g,
                                   (__attribute__((address_space(3))) void*)l, 16, 0, 0);
}

// Counted-vmcnt acquire: certify all but the newest VM loads, then barrier.
#define ACQ(VM) do {                                                     \
    asm volatile("s_waitcnt vmcnt(" VM ")" ::: "memory");                \
    __builtin_amdgcn_s_barrier();                                        \
    asm volatile("" ::: "memory");                                       \
  } while (0)
// Release barrier: reads of the outgoing buffer retired before this point.
#define REL() do {                                                       \
    asm volatile("" ::: "memory");                                       \
    __builtin_amdgcn_s_barrier();                                        \
  } while (0)

// ------------------------------------------------------------------
// s1 = embed @ d1_w + d1_b  (4x64);  s2 = context @ d2_w + d2_b (4x128)
__global__ __launch_bounds__(256) void scales_kernel(
    const float* __restrict__ embed, const float* __restrict__ context,
    const float* __restrict__ d1w, const float* __restrict__ d1b,
    const float* __restrict__ d2w, const float* __restrict__ d2b,
    float* __restrict__ s1, float* __restrict__ s2) {
  int tid = blockIdx.x * 256 + threadIdx.x;
  if (tid < 256) {
    int b = tid >> 6, c = tid & 63;
    float acc = d1b[c];
    for (int e = 0; e < 256; ++e) acc += embed[b * 256 + e] * d1w[e * 64 + c];
    s1[tid] = acc;
  } else if (tid < 768) {
    int o = tid - 256;
    int b = o >> 7, c = o & 127;
    float acc = d2b[c];
    for (int e = 0; e < 256; ++e) acc += context[b * 256 + e] * d2w[e * 128 + c];
    s2[o] = acc;
  }
}

// ------------------------------------------------------------------
// Weight repack: w[co][ci][kz][ky][kx] fp32 -> wt[tap][co][ci] bf16
__global__ __launch_bounds__(256) void prep_w_kernel(
    const float* __restrict__ w20, const float* __restrict__ w21,
    const float* __restrict__ wdn, const float* __restrict__ rsw,
    short* __restrict__ wt20, short* __restrict__ wt21,
    short* __restrict__ wtdn, short* __restrict__ rw) {
  for (int o = blockIdx.x * 256 + threadIdx.x; o < 1114112; o += gridDim.x * 256) {
    if (o < 221184) {                       // wt20: 27*128*64
      int t = o >> 13, rem = o & 8191, co = rem >> 6, ci = rem & 63;
      wt20[o] = f2bf(w20[(co * 64 + ci) * 27 + t]);
    } else if (o < 663552) {                // wt21: 27*128*128
      int p = o - 221184;
      int t = p >> 14, rem = p & 16383, co = rem >> 7, ci = rem & 127;
      wt21[p] = f2bf(w21[(co * 128 + ci) * 27 + t]);
    } else if (o < 1105920) {               // wtdn: 27*128*128
      int p = o - 663552;
      int t = p >> 14, rem = p & 16383, co = rem >> 7, ci = rem & 127;
      wtdn[p] = f2bf(wdn[(co * 128 + ci) * 27 + t]);
    } else {                                // rw: 128*64 (1x1x1, same order)
      int p = o - 1105920;
      rw[p] = f2bf(rsw[p]);
    }
  }
}

// ------------------------------------------------------------------
// h1[b][z][y][x][ci] bf16 = swish(x + s1[b][ci]); channels-last via LDS transpose
__global__ __launch_bounds__(256) void prep_h1_kernel(
    const float* __restrict__ xin, const float* __restrict__ s1,
    short* __restrict__ h1) {
  __shared__ __align__(16) short sm[128 * 72];
  const int tid = threadIdx.x;
  const int gid = blockIdx.x;               // = b*1024 + z*128 + y
  const int y = gid & 127, z = (gid >> 7) & 7, b = gid >> 10;
  const float* xbase = xin + (size_t)b * 8388608 + (size_t)z * 16384 + (size_t)y * 128;
#pragma unroll
  for (int i = 0; i < 8; ++i) {             // 2048 float4
    int e = i * 256 + tid;
    int ci = e >> 5, x4 = e & 31;
    float4 v = *(const float4*)(xbase + (size_t)ci * 131072 + x4 * 4);
    float s = s1[b * 64 + ci];
    sm[(x4 * 4 + 0) * 72 + ci] = f2bf(swish_f(v.x + s));
    sm[(x4 * 4 + 1) * 72 + ci] = f2bf(swish_f(v.y + s));
    sm[(x4 * 4 + 2) * 72 + ci] = f2bf(swish_f(v.z + s));
    sm[(x4 * 4 + 3) * 72 + ci] = f2bf(swish_f(v.w + s));
  }
  __syncthreads();
  short* orow = h1 + (size_t)gid * 8192;
#pragma unroll
  for (int i = 0; i < 4; ++i) {             // 1024 vec8
    int e = i * 256 + tid;
    int xx = e >> 3, c8 = e & 7;
    *(bf16x8*)(orow + e * 8) = *(const bf16x8*)(&sm[xx * 72 + c8 * 8]);
  }
}

// ------------------------------------------------------------------
// conv20: h2 = swish(conv3d(h1, w20) + b20) * s2   (Cin=64 -> Cout=128), bf16 out
// Cross-step bb prefetch, spill-safe: register arrays only touched via macros
// with textual names + compile-time indices (no address-taking; rule #20).
__global__ __launch_bounds__(256, 3) void conv20_kernel(
    const short* __restrict__ h1, const short* __restrict__ wt,
    const float* __restrict__ b20, const float* __restrict__ s2,
    short* __restrict__ h2) {
  __shared__ __align__(16) short sm[24704];   // inbuf 8320 + wbuf 2*8192
  const int tid = threadIdx.x;
  const int bi = blockIdx.x;
  const int xcd = bi & 7, slot = bi >> 3;
  const int yo = slot & 15, z = (slot >> 4) & 7, b = slot >> 7;
  const int y = xcd * 16 + yo;
  const int gid = b * 1024 + z * 128 + y;
  const int lane = tid & 63, wave = tid >> 6;
  const int wm = wave >> 1, wn = wave & 1;
  const int q = lane >> 4, n0 = lane & 15;
  const bf16x8 zz = {0, 0, 0, 0, 0, 0, 0, 0};
  short* inbuf = sm;                          // [130 x][64 ci], 8-unit xor swizzle
  f32x4 acc[4][4];
#pragma unroll
  for (int i = 0; i < 4; ++i)
#pragma unroll
    for (int j = 0; j < 4; ++j) acc[i][j] = (f32x4){0.f, 0.f, 0.f, 0.f};

  auto wstage = [&](int s) {                  // tap s -> wbuf[s&1]; [co 128][8 units, u^co swz]
    const short* src = wt + (s << 13);
    short* dst = sm + 8320 + ((s & 1) << 13);
    int r = lane >> 3, ss = lane & 7;
#pragma unroll
    for (int i = 0; i < 4; ++i) {
      int c = wave * 4 + i;
      gld_lds16(src + ((c * 8 + r) << 6) + ((ss ^ r) << 3), dst + (c << 9));
    }
  };
  auto instage = [&](int it) {                // row (kz,ky)=it -> inbuf rows 1..128
    int kz = it / 3, ky = it - kz * 3;
    int zi = z + kz - 1, yi = y + ky - 1;
    if (zi >= 0 && zi < 8 && yi >= 0 && yi < 128) {
      const short* row = h1 + ((size_t)(b * 1024 + zi * 128 + yi) << 13);
#pragma unroll
      for (int i = 0; i < 4; ++i) {
        int x0 = 1 + 8 * (wave * 4 + i);
        int x = x0 + (lane >> 3);
        int c8 = (lane & 7) ^ (x & 7);
        gld_lds16(row + ((x - 1) << 6) + (c8 << 3), inbuf + (x0 << 6));
      }
    } else {
#pragma unroll
      for (int i = 0; i < 4; ++i)
        *(bf16x8*)(&inbuf[64 + (i * 256 + tid) * 8]) = zz;
      asm volatile("s_waitcnt lgkmcnt(0)" ::: "memory");
    }
  };

  if (tid < 16) {                             // halo rows 0,129 zero (persist)
    int hf = tid >> 3, u = tid & 7;
    *(bf16x8*)(&inbuf[(hf ? 129 : 0) * 64 + u * 8]) = zz;
  }
  wstage(0);
  instage(0);
  __syncthreads();                            // prologue: one full drain (once)

  bf16x8 af[2][4], bbA[2][4], bbB[2][4];

#define C20_AF(PAR)                                                            \
  { const short* w_ = sm + 8320 + ((PAR) << 13);                               \
    _Pragma("unroll") for (int ch = 0; ch < 2; ++ch)                           \
    _Pragma("unroll") for (int i = 0; i < 4; ++i)                              \
      af[ch][i] = *(const bf16x8*)(&w_[(wm * 64 + i * 16 + n0) * 64 +          \
                                       (((ch * 4 + q) ^ (n0 & 7)) << 3)]); }
#define C20_BB(KX, BB)                                                         \
  { _Pragma("unroll") for (int ch = 0; ch < 2; ++ch)                           \
    _Pragma("unroll") for (int j = 0; j < 4; ++j) {                            \
      int xx = wn * 64 + j * 16 + n0 + (KX);                                   \
      BB[ch][j] = *(const bf16x8*)(&inbuf[xx * 64 +                            \
                                          (((ch * 4 + q) ^ (xx & 7)) << 3)]); } }
#define C20_MFMA(BB)                                                           \
  { __builtin_amdgcn_s_setprio(1);                                             \
    _Pragma("unroll") for (int ch = 0; ch < 2; ++ch)                           \
    _Pragma("unroll") for (int i = 0; i < 4; ++i)                              \
    _Pragma("unroll") for (int j = 0; j < 4; ++j)                              \
      acc[i][j] = __builtin_amdgcn_mfma_f32_16x16x32_bf16(af[ch][i], BB[ch][j],\
                                                          acc[i][j], 0, 0, 0); \
    __builtin_amdgcn_s_setprio(0); }

  for (int g = 0; g < 8; ++g) {               // groups of 3 steps (one (kz,ky) row)
    const int s3 = g * 3;
    wstage(s3 + 1); ACQ("4");                 // certify wstage(s3) [+instage(g)]
    C20_AF(g & 1);
    C20_BB(0, bbA);
    C20_BB(1, bbB);                           // prefetch kx=1 (hides under MFMA)
    C20_MFMA(bbA);
    REL();
    wstage(s3 + 2); ACQ("4");
    C20_AF((g & 1) ^ 1);
    C20_BB(2, bbA);                           // prefetch kx=2
    C20_MFMA(bbB);
    REL();
    wstage(s3 + 3); ACQ("4");
    C20_AF(g & 1);
    C20_MFMA(bbA);                            // no bb read: fully hidden step
    REL();
    instage(g + 1);                           // in flight; certified by next ACQ
  }
  {                                           // tail: s=24,25,26 (inbuf row 8)
    wstage(25); ACQ("4"); C20_AF(0);
    C20_BB(0, bbA); C20_BB(1, bbB);
    C20_MFMA(bbA); REL();
    wstage(26); ACQ("4"); C20_AF(1);
    C20_BB(2, bbA);
    C20_MFMA(bbB); REL();
    ACQ("0"); C20_AF(0);
    C20_MFMA(bbA); REL();
  }
#undef C20_AF
#undef C20_BB
#undef C20_MFMA
  // epilogue: bias + swish + s2, transpose through LDS, contiguous bf16 row out
#pragma unroll
  for (int i = 0; i < 4; ++i) {
    const int mb = wm * 64 + i * 16 + q * 4;
    const float4 bias = *(const float4*)(b20 + mb);
    const float4 sc = *(const float4*)(s2 + b * 128 + mb);
#pragma unroll
    for (int j = 0; j < 4; ++j) {
      const int n = wn * 64 + j * 16 + n0;
      bf16x4v pk;
      pk.x = f2bf(swish_f(acc[i][j][0] + bias.x) * sc.x);
      pk.y = f2bf(swish_f(acc[i][j][1] + bias.y) * sc.y);
      pk.z = f2bf(swish_f(acc[i][j][2] + bias.z) * sc.z);
      pk.w = f2bf(swish_f(acc[i][j][3] + bias.w) * sc.w);
      *(bf16x4v*)(&sm[n * 136 + mb]) = pk;
    }
  }
  __syncthreads();
  short* orow = h2 + (size_t)gid * 16384;
#pragma unroll
  for (int i = 0; i < 8; ++i) {               // 2048 vec8
    int e = i * 256 + tid;
    int xx = e >> 4, c8 = e & 15;
    *(bf16x8*)(orow + e * 8) = *(const bf16x8*)(&sm[xx * 136 + c8 * 8]);
  }
}

// ------------------------------------------------------------------
// conv21: h3 = swish(conv3d(h2, w21) + conv1x1(x, res_w) + res_b)  (128->128), bf16
// Cross-step bb prefetch (period-6), spill-safe macro form.
__global__ __launch_bounds__(256, 2) void conv21_kernel(
    const short* __restrict__ h2, const short* __restrict__ wt,
    const float* __restrict__ xin, const short* __restrict__ rw,
    const float* __restrict__ res_b, short* __restrict__ h3) {
  __shared__ __align__(16) short sm[33024];   // inbuf 16640 + wbuf 2*8192
  const int tid = threadIdx.x;
  const int bi = blockIdx.x;
  const int xcd = bi & 7, slot = bi >> 3;
  const int yo = slot & 15, z = (slot >> 4) & 7, b = slot >> 7;
  const int y = xcd * 16 + yo;
  const int gid = b * 1024 + z * 128 + y;
  const int lane = tid & 63, wave = tid >> 6;
  const int wm = wave >> 1, wn = wave & 1;
  const int q = lane >> 4, n0 = lane & 15;
  const bf16x8 zz = {0, 0, 0, 0, 0, 0, 0, 0};
  short* inbuf = sm;                          // [130 x][128 ci], 16-unit xor swizzle
  f32x4 acc[4][4];
#pragma unroll
  for (int i = 0; i < 4; ++i)
#pragma unroll
    for (int j = 0; j < 4; ++j) acc[i][j] = (f32x4){0.f, 0.f, 0.f, 0.f};

  auto wstage = [&](int s) {                  // half-tap s -> wbuf[s&1]; [co 128][8 units, u^co]
    int it6 = s / 6, sub = s - it6 * 6, kx = sub >> 1, ch2 = sub & 1;
    const short* src = wt + (((it6 * 3 + kx) << 14) + (ch2 << 6));
    short* dst = sm + 16640 + ((s & 1) << 13);
    int r = lane >> 3, ss = lane & 7;
#pragma unroll
    for (int i = 0; i < 4; ++i) {
      int c = wave * 4 + i;
      gld_lds16(src + ((c * 8 + r) << 7) + ((ss ^ r) << 3), dst + (c << 9));
    }
  };
  auto instage = [&](int it) {
    int kz = it / 3, ky = it - kz * 3;
    int zi = z + kz - 1, yi = y + ky - 1;
    if (zi >= 0 && zi < 8 && yi >= 0 && yi < 128) {
      const short* row = h2 + ((size_t)(b * 1024 + zi * 128 + yi) << 14);
#pragma unroll
      for (int i = 0; i < 8; ++i) {
        int x0 = 1 + 4 * (wave * 8 + i);
        int x = x0 + (lane >> 4);
        int c8 = (lane & 15) ^ (x & 15);
        gld_lds16(row + ((x - 1) << 7) + (c8 << 3), inbuf + (x0 << 7));
      }
    } else {
#pragma unroll
      for (int i = 0; i < 8; ++i)
        *(bf16x8*)(&inbuf[128 + (i * 256 + tid) * 8]) = zz;
      asm volatile("s_waitcnt lgkmcnt(0)" ::: "memory");
    }
  };

  if (tid < 32) {                             // halo rows 0,129 zero (persist)
    int hf = tid >> 4, u = tid & 15;
    *(bf16x8*)(&inbuf[(hf ? 129 : 0) * 128 + u * 8]) = zz;
  }
  wstage(0);
  instage(0);
  __syncthreads();                            // prologue: one full drain (once)

  bf16x8 af[2][4], bbA[2][4], bbB[2][4];
  float4 xv[8];

#define C21_AF(PAR)                                                            \
  { const short* w_ = sm + 16640 + ((PAR) << 13);                              \
    _Pragma("unroll") for (int chL = 0; chL < 2; ++chL)                        \
    _Pragma("unroll") for (int i = 0; i < 4; ++i)                              \
      af[chL][i] = *(const bf16x8*)(&w_[(wm * 64 + i * 16 + n0) * 64 +         \
                                        (((chL * 4 + q) ^ (n0 & 7)) << 3)]); }
#define C21_BB(KX, CH2, BB)                                                    \
  { _Pragma("unroll") for (int chL = 0; chL < 2; ++chL) {                      \
      const int ch = (CH2) * 2 + chL;                                          \
      _Pragma("unroll") for (int j = 0; j < 4; ++j) {                          \
        int xx = wn * 64 + j * 16 + n0 + (KX);                                 \
        BB[chL][j] = *(const bf16x8*)(&inbuf[(xx << 7) +                       \
                                      (((ch * 4 + q) ^ (xx & 15)) << 3)]); } } }
#define C21_MFMA(BB)                                                           \
  { __builtin_amdgcn_s_setprio(1);                                             \
    _Pragma("unroll") for (int chL = 0; chL < 2; ++chL)                        \
    _Pragma("unroll") for (int i = 0; i < 4; ++i)                              \
    _Pragma("unroll") for (int j = 0; j < 4; ++j)                              \
      acc[i][j] = __builtin_amdgcn_mfma_f32_16x16x32_bf16(af[chL][i], BB[chL][j],\
                                                          acc[i][j], 0, 0, 0); \
    __builtin_amdgcn_s_setprio(0); }

  for (int g = 0; g < 8; ++g) {               // groups of 6 steps (one (kz,ky) row)
    const int s6 = g * 6;
    wstage(s6 + 1); ACQ("4");                 // certify wstage(s6) [+instage(g)]
    C21_AF(0);
    C21_BB(0, 0, bbA);
    C21_BB(0, 1, bbB);                        // prefetch (kx0,ch1)
    C21_MFMA(bbA); REL();
    wstage(s6 + 2); ACQ("4"); C21_AF(1);
    C21_BB(1, 0, bbA);                        // prefetch (kx1,ch0)
    C21_MFMA(bbB); REL();
    wstage(s6 + 3); ACQ("4"); C21_AF(0);
    C21_BB(1, 1, bbB);                        // prefetch (kx1,ch1)
    C21_MFMA(bbA); REL();
    wstage(s6 + 4); ACQ("4"); C21_AF(1);
    C21_BB(2, 0, bbA);                        // prefetch (kx2,ch0)
    C21_MFMA(bbB); REL();
    wstage(s6 + 5); ACQ("4"); C21_AF(0);
    C21_BB(2, 1, bbB);                        // prefetch (kx2,ch1)
    C21_MFMA(bbA); REL();
    wstage(s6 + 6); ACQ("4"); C21_AF(1);
    C21_MFMA(bbB); REL();                     // no bb read
    instage(g + 1);
  }
  {                                           // tail: s=48..53 (inbuf row 8)
    wstage(49); ACQ("4"); C21_AF(0);
    C21_BB(0, 0, bbA); C21_BB(0, 1, bbB);
    C21_MFMA(bbA); REL();
    wstage(50); ACQ("4"); C21_AF(1);
    C21_BB(1, 0, bbA);
    C21_MFMA(bbB); REL();
    wstage(51); ACQ("4"); C21_AF(0);
    C21_BB(1, 1, bbB);
    C21_MFMA(bbA); REL();
    wstage(52); ACQ("4");
    {                                         // prefetch fp32 res row to regs
      const float* xb = xin + (size_t)b * 8388608 + (size_t)z * 16384 + (size_t)y * 128;
#pragma unroll
      for (int i = 0; i < 8; ++i) {
        int e = i * 256 + tid;
        int ci = e >> 5, x4 = e & 31;
        xv[i] = *(const float4*)(xb + (size_t)ci * 131072 + x4 * 4);
      }
    }
    C21_AF(1);
    C21_BB(2, 0, bbA);
    C21_MFMA(bbB); REL();
    wstage(53); ACQ("12");                    // certify w52; xv(8)+w53(4) in flight
    C21_AF(0);
    C21_BB(2, 1, bbB);
    C21_MFMA(bbA); REL();
    ACQ("0");                                 // certify w53 (drains xv too)
    C21_AF(1);
    C21_MFMA(bbB); REL();
  }
#undef C21_AF
#undef C21_BB
#undef C21_MFMA
  // res 1x1 tap: write x row (bf16, 64-ci swizzle incl. (xx>>3) bit) into free wbuf
  short* rbuf = sm + 16640;                   // s=53 read parity 1; buf 0 free
  {
#pragma unroll
    for (int i = 0; i < 8; ++i) {
      int e = i * 256 + tid;
      int ci = e >> 5, x4 = e & 31;
      int u0 = ci >> 3, cl = ci & 7;
#pragma unroll
      for (int k = 0; k < 4; ++k) {
        int xx = x4 * 4 + k;
        float fv = (k == 0) ? xv[i].x : (k == 1) ? xv[i].y : (k == 2) ? xv[i].z : xv[i].w;
        rbuf[xx * 64 + ((u0 ^ (xx & 7) ^ ((xx >> 3) & 7)) << 3) + cl] = f2bf(fv);
      }
    }
  }
  __syncthreads();
#pragma unroll
  for (int ch = 0; ch < 2; ++ch) {
    bf16x8 raf[4], rbb[4];
#pragma unroll
    for (int i = 0; i < 4; ++i)
      raf[i] = *(const bf16x8*)(rw + (wm * 64 + i * 16 + n0) * 64 + ch * 32 + q * 8);
#pragma unroll
    for (int j = 0; j < 4; ++j) {
      int xx = wn * 64 + j * 16 + n0;
      rbb[j] = *(const bf16x8*)(&rbuf[xx * 64 + (((ch * 4 + q) ^ (xx & 7) ^ ((xx >> 3) & 7)) << 3)]);
    }
#pragma unroll
    for (int i = 0; i < 4; ++i)
#pragma unroll
      for (int j = 0; j < 4; ++j)
        acc[i][j] = __builtin_amdgcn_mfma_f32_16x16x32_bf16(raf[i], rbb[j], acc[i][j], 0, 0, 0);
  }
  __syncthreads();
  // epilogue: + res_b, swish, bf16 out (channels-last)
#pragma unroll
  for (int i = 0; i < 4; ++i) {
    const int mb = wm * 64 + i * 16 + q * 4;
    const float4 bias = *(const float4*)(res_b + mb);
#pragma unroll
    for (int j = 0; j < 4; ++j) {
      const int n = wn * 64 + j * 16 + n0;
      bf16x4v pk;
      pk.x = f2bf(swish_f(acc[i][j][0] + bias.x));
      pk.y = f2bf(swish_f(acc[i][j][1] + bias.y));
      pk.z = f2bf(swish_f(acc[i][j][2] + bias.z));
      pk.w = f2bf(swish_f(acc[i][j][3] + bias.w));
      *(bf16x4v*)(&sm[n * 136 + mb]) = pk;
    }
  }
  __syncthreads();
  short* orow = h3 + (size_t)gid * 16384;
#pragma unroll
  for (int i = 0; i < 8; ++i) {
    int e = i * 256 + tid;
    int xx = e >> 4, c8 = e & 15;
    *(bf16x8*)(orow + e * 8) = *(const bf16x8*)(&sm[xx * 136 + c8 * 8]);
  }
}

// ------------------------------------------------------------------
// down: out = conv3d(h3, down_w, stride (1,2,2), pad z only) + down_b, fp32 NCDHW
__global__ __launch_bounds__(256, 2) void down_kernel(
    const short* __restrict__ h3, const short* __restrict__ wt,
    const float* __restrict__ dnb, float* __restrict__ out) {
  __shared__ __align__(16) short sm[33024];   // inbuf 16640 + wbuf 2*8192
  const int tid = threadIdx.x;
  const int bi = blockIdx.x;                  // 4*8*63 = 2016
  const int o = (bi & 7) * 252 + (bi >> 3);
  const int yo = o % 63;
  const int zb = o / 63;
  const int z = zb & 7, b = zb >> 3;
  const int lane = tid & 63, wave = tid >> 6;
  const int wm = wave >> 1, wn = wave & 1;
  const int q = lane >> 4, n0 = lane & 15;
  const bf16x8 zz = {0, 0, 0, 0, 0, 0, 0, 0};
  short* inbuf = sm;                          // [130 x][128 ci], rows 0..127 data
  f32x4 acc[4][2];
#pragma unroll
  for (int i = 0; i < 4; ++i)
#pragma unroll
    for (int j = 0; j < 2; ++j) acc[i][j] = (f32x4){0.f, 0.f, 0.f, 0.f};

  auto wstage = [&](int s) {
    int it6 = s / 6, sub = s - it6 * 6, kx = sub >> 1, ch2 = sub & 1;
    const short* src = wt + (((it6 * 3 + kx) << 14) + (ch2 << 6));
    short* dst = sm + 16640 + ((s & 1) << 13);
    int r = lane >> 3, ss = lane & 7;
#pragma unroll
    for (int i = 0; i < 4; ++i) {
      int c = wave * 4 + i;
      gld_lds16(src + ((c * 8 + r) << 7) + ((ss ^ r) << 3), dst + (c << 9));
    }
  };
  auto instage = [&](int it) {
    int kz = it / 3, ky = it - kz * 3;
    int zi = z + kz - 1;
    int yi = 2 * yo + ky;                     // always in range
    if (zi >= 0 && zi < 8) {
      const short* row = h3 + ((size_t)(b * 1024 + zi * 128 + yi) << 14);
#pragma unroll
      for (int i = 0; i < 8; ++i) {
        int x0 = 4 * (wave * 8 + i);          // no x shift
        int x = x0 + (lane >> 4);
        int c8 = (lane & 15) ^ (x & 15);
        gld_lds16(row + (x << 7) + (c8 << 3), inbuf + (x0 << 7));
      }
    } else {
#pragma unroll
      for (int i = 0; i < 8; ++i)
        *(bf16x8*)(&inbuf[(i * 256 + tid) * 8]) = zz;
      asm volatile("s_waitcnt lgkmcnt(0)" ::: "memory");
    }
  };

  if (tid < 32) {                             // rows 128,129 zero (dead n=63 lanes)
    int hf = tid >> 4, u = tid & 15;
    *(bf16x8*)(&inbuf[(128 + hf) * 128 + u * 8]) = zz;
  }
  wstage(0);
  instage(0);
  __syncthreads();                            // prologue: one full drain (once)

  bf16x8 af[2][4], bbA[2][2], bbB[2][2];

#define DN_AF(PAR)                                                             \
  { const short* w_ = sm + 16640 + ((PAR) << 13);                              \
    _Pragma("unroll") for (int chL = 0; chL < 2; ++chL)                        \
    _Pragma("unroll") for (int i = 0; i < 4; ++i)                              \
      af[chL][i] = *(const bf16x8*)(&w_[(wm * 64 + i * 16 + n0) * 64 +         \
                                        (((chL * 4 + q) ^ (n0 & 7)) << 3)]); }
#define DN_BB(KX, CH2, BB)                                                     \
  { _Pragma("unroll") for (int chL = 0; chL < 2; ++chL) {                      \
      const int ch = (CH2) * 2 + chL;                                          \
      _Pragma("unroll") for (int j = 0; j < 2; ++j) {                          \
        int xp = 2 * (wn * 32 + j * 16 + n0) + (KX);                           \
        BB[chL][j] = *(const bf16x8*)(&inbuf[(xp << 7) +                       \
                                      (((ch * 4 + q) ^ (xp & 15)) << 3)]); } } }
#define DN_MFMA(BB)                                                            \
  { __builtin_amdgcn_s_setprio(1);                                             \
    _Pragma("unroll") for (int chL = 0; chL < 2; ++chL)                        \
    _Pragma("unroll") for (int i = 0; i < 4; ++i)                              \
    _Pragma("unroll") for (int j = 0; j < 2; ++j)                              \
      acc[i][j] = __builtin_amdgcn_mfma_f32_16x16x32_bf16(af[chL][i], BB[chL][j],\
                                                          acc[i][j], 0, 0, 0); \
    __builtin_amdgcn_s_setprio(0); }

  for (int g = 0; g < 8; ++g) {
    const int s6 = g * 6;
    wstage(s6 + 1); ACQ("4"); DN_AF(0);
    DN_BB(0, 0, bbA);
    DN_BB(0, 1, bbB);
    DN_MFMA(bbA); REL();
    wstage(s6 + 2); ACQ("4"); DN_AF(1);
    DN_BB(1, 0, bbA);
    DN_MFMA(bbB); REL();
    wstage(s6 + 3); ACQ("4"); DN_AF(0);
    DN_BB(1, 1, bbB);
    DN_MFMA(bbA); REL();
    wstage(s6 + 4); ACQ("4"); DN_AF(1);
    DN_BB(2, 0, bbA);
    DN_MFMA(bbB); REL();
    wstage(s6 + 5); ACQ("4"); DN_AF(0);
    DN_BB(2, 1, bbB);
    DN_MFMA(bbA); REL();
    wstage(s6 + 6); ACQ("4"); DN_AF(1);
    DN_MFMA(bbB); REL();
    instage(g + 1);
  }
  {                                           // tail: s=48..53
    wstage(49); ACQ("4"); DN_AF(0);
    DN_BB(0, 0, bbA); DN_BB(0, 1, bbB);
    DN_MFMA(bbA); REL();
    wstage(50); ACQ("4"); DN_AF(1);
    DN_BB(1, 0, bbA);
    DN_MFMA(bbB); REL();
    wstage(51); ACQ("4"); DN_AF(0);
    DN_BB(1, 1, bbB);
    DN_MFMA(bbA); REL();
    wstage(52); ACQ("4"); DN_AF(1);
    DN_BB(2, 0, bbA);
    DN_MFMA(bbB); REL();
    wstage(53); ACQ("4"); DN_AF(0);
    DN_BB(2, 1, bbB);
    DN_MFMA(bbA); REL();
    ACQ("0"); DN_AF(1);
    DN_MFMA(bbB); REL();
  }
#undef DN_AF
#undef DN_BB
#undef DN_MFMA
  // epilogue: + down_b, fp32 transpose in LDS (stride 133: conflict-free), NCDHW out
  float* fsm = (float*)sm;
#pragma unroll
  for (int i = 0; i < 4; ++i) {
    const int mb = wm * 64 + i * 16 + q * 4;
    const float4 bias = *(const float4*)(dnb + mb);
#pragma unroll
    for (int j = 0; j < 2; ++j) {
      const int n = wn * 32 + j * 16 + n0;
      f32x4 v;
      v[0] = acc[i][j][0] + bias.x;
      v[1] = acc[i][j][1] + bias.y;
      v[2] = acc[i][j][2] + bias.z;
      v[3] = acc[i][j][3] + bias.w;
      *(f32x4*)(&fsm[n * 133 + mb]) = v;
    }
  }
  __syncthreads();
#pragma unroll
  for (int it = 0; it < 32; ++it) {           // 128 co x 64 lanes (63 valid)
    int idx = it * 256 + tid;
    int co = idx >> 6, xl = idx & 63;
    if (xl < 63)
      out[((size_t)(b * 128 + co) * 8 + z) * 3969 + yo * 63 + xl] = fsm[xl * 133 + co];
  }
}

// ------------------------------------------------------------------
extern "C" void kernel_launch(void* const* d_in, const int* in_sizes, int n_in,
                              void* d_out, int out_size, void* d_ws, size_t ws_size,
                              hipStream_t stream) {
  const float* x       = (const float*)d_in[0];
  const float* embed   = (const float*)d_in[1];
  const float* context = (const float*)d_in[2];
  const float* w20     = (const float*)d_in[3];
  const float* b20     = (const float*)d_in[4];
  const float* w21     = (const float*)d_in[5];
  const float* d1w     = (const float*)d_in[6];
  const float* d1b     = (const float*)d_in[7];
  const float* d2w     = (const float*)d_in[8];
  const float* d2b     = (const float*)d_in[9];
  const float* resw    = (const float*)d_in[10];
  const float* resb    = (const float*)d_in[11];
  const float* dnw     = (const float*)d_in[12];
  const float* dnb     = (const float*)d_in[13];
  float* out = (float*)d_out;
  char* ws = (char*)d_ws;
  float* s1   = (float*)(ws + 0);          // 1 KB
  float* s2   = (float*)(ws + 1024);       // 2 KB
  short* wt20 = (short*)(ws + 4096);       // 432 KB
  short* wt21 = (short*)(ws + 446464);     // 864 KB
  short* wtdn = (short*)(ws + 1331200);    // 864 KB
  short* rw   = (short*)(ws + 2215936);    // 16 KB
  short* h1   = (short*)(ws + 2232320);    // 64 MB  [b][z][y][x][ci=64] bf16
  short* h2   = (short*)(ws + 69341184);   // 128 MB [b][z][y][x][ci=128] bf16
  short* h3   = (short*)(ws + 203558912);  // 128 MB [b][z][y][x][ci=128] bf16

  scales_kernel<<<3, 256, 0, stream>>>(embed, context, d1w, d1b, d2w, d2b, s1, s2);
  prep_w_kernel<<<1088, 256, 0, stream>>>(w20, w21, dnw, resw, wt20, wt21, wtdn, rw);
  prep_h1_kernel<<<4096, 256, 0, stream>>>(x, s1, h1);
  conv20_kernel<<<4096, 256, 0, stream>>>(h1, wt20, b20, s2, h2);
  conv21_kernel<<<4096, 256, 0, stream>>>(h2, wt21, x, rw, resb, h3);
  down_kernel<<<2016, 256, 0, stream>>>(h3, wtdn, dnb, out);
}

// Round 5
// 1007.125 us; speedup vs baseline: 1.3922x; 1.2592x over previous
//
#include <hip/hip_runtime.h>
#include <cstdint>
#include <cstddef>

typedef __attribute__((ext_vector_type(8))) short bf16x8;
typedef __attribute__((ext_vector_type(4))) short bf16x4v;
typedef __attribute__((ext_vector_type(4))) float f32x4;

__device__ inline short f2bf(float f) {
  union { float f; unsigned u; } c; c.f = f;
  unsigned u = c.u;
  unsigned r = (u + 0x7fffu + ((u >> 16) & 1u)) >> 16;
  return (short)r;
}
__device__ inline float swish_f(float v) { return v / (1.f + __expf(-v)); }

__device__ inline void gld_lds16(const void* g, void* l) {
  __builtin_amdgcn_global_load_lds((const __attribute__((address_space(1))) void*)g,
                                   (__attribute__((address_space(3))) void*)l, 16, 0, 0);
}

// Counted-vmcnt acquire: certify all but the newest VM loads, then barrier.
#define ACQ(VM) do {                                                     \
    asm volatile("s_waitcnt vmcnt(" VM ")" ::: "memory");                \
    __builtin_amdgcn_s_barrier();                                        \
    asm volatile("" ::: "memory");                                       \
  } while (0)
// Release barrier: reads of the outgoing buffer retired before this point.
#define REL() do {                                                       \
    asm volatile("" ::: "memory");                                       \
    __builtin_amdgcn_s_barrier();                                        \
  } while (0)

// ------------------------------------------------------------------
// s1 = embed @ d1_w + d1_b  (4x64);  s2 = context @ d2_w + d2_b (4x128)
__global__ __launch_bounds__(256) void scales_kernel(
    const float* __restrict__ embed, const float* __restrict__ context,
    const float* __restrict__ d1w, const float* __restrict__ d1b,
    const float* __restrict__ d2w, const float* __restrict__ d2b,
    float* __restrict__ s1, float* __restrict__ s2) {
  int tid = blockIdx.x * 256 + threadIdx.x;
  if (tid < 256) {
    int b = tid >> 6, c = tid & 63;
    float acc = d1b[c];
    for (int e = 0; e < 256; ++e) acc += embed[b * 256 + e] * d1w[e * 64 + c];
    s1[tid] = acc;
  } else if (tid < 768) {
    int o = tid - 256;
    int b = o >> 7, c = o & 127;
    float acc = d2b[c];
    for (int e = 0; e < 256; ++e) acc += context[b * 256 + e] * d2w[e * 128 + c];
    s2[o] = acc;
  }
}

// ------------------------------------------------------------------
// Weight repack: w[co][ci][kz][ky][kx] fp32 -> wt[tap][co][ci] bf16
__global__ __launch_bounds__(256) void prep_w_kernel(
    const float* __restrict__ w20, const float* __restrict__ w21,
    const float* __restrict__ wdn, const float* __restrict__ rsw,
    short* __restrict__ wt20, short* __restrict__ wt21,
    short* __restrict__ wtdn, short* __restrict__ rw) {
  for (int o = blockIdx.x * 256 + threadIdx.x; o < 1114112; o += gridDim.x * 256) {
    if (o < 221184) {                       // wt20: 27*128*64
      int t = o >> 13, rem = o & 8191, co = rem >> 6, ci = rem & 63;
      wt20[o] = f2bf(w20[(co * 64 + ci) * 27 + t]);
    } else if (o < 663552) {                // wt21: 27*128*128
      int p = o - 221184;
      int t = p >> 14, rem = p & 16383, co = rem >> 7, ci = rem & 127;
      wt21[p] = f2bf(w21[(co * 128 + ci) * 27 + t]);
    } else if (o < 1105920) {               // wtdn: 27*128*128
      int p = o - 663552;
      int t = p >> 14, rem = p & 16383, co = rem >> 7, ci = rem & 127;
      wtdn[p] = f2bf(wdn[(co * 128 + ci) * 27 + t]);
    } else {                                // rw: 128*64 (1x1x1, same order)
      int p = o - 1105920;
      rw[p] = f2bf(rsw[p]);
    }
  }
}

// ------------------------------------------------------------------
// h1[b][z][y][x][ci] bf16 = swish(x + s1[b][ci]); channels-last via LDS transpose
__global__ __launch_bounds__(256) void prep_h1_kernel(
    const float* __restrict__ xin, const float* __restrict__ s1,
    short* __restrict__ h1) {
  __shared__ __align__(16) short sm[128 * 72];
  const int tid = threadIdx.x;
  const int gid = blockIdx.x;               // = b*1024 + z*128 + y
  const int y = gid & 127, z = (gid >> 7) & 7, b = gid >> 10;
  const float* xbase = xin + (size_t)b * 8388608 + (size_t)z * 16384 + (size_t)y * 128;
#pragma unroll
  for (int i = 0; i < 8; ++i) {             // 2048 float4
    int e = i * 256 + tid;
    int ci = e >> 5, x4 = e & 31;
    float4 v = *(const float4*)(xbase + (size_t)ci * 131072 + x4 * 4);
    float s = s1[b * 64 + ci];
    sm[(x4 * 4 + 0) * 72 + ci] = f2bf(swish_f(v.x + s));
    sm[(x4 * 4 + 1) * 72 + ci] = f2bf(swish_f(v.y + s));
    sm[(x4 * 4 + 2) * 72 + ci] = f2bf(swish_f(v.z + s));
    sm[(x4 * 4 + 3) * 72 + ci] = f2bf(swish_f(v.w + s));
  }
  __syncthreads();
  short* orow = h1 + (size_t)gid * 8192;
#pragma unroll
  for (int i = 0; i < 4; ++i) {             // 1024 vec8
    int e = i * 256 + tid;
    int xx = e >> 3, c8 = e & 7;
    *(bf16x8*)(orow + e * 8) = *(const bf16x8*)(&sm[xx * 72 + c8 * 8]);
  }
}

// ------------------------------------------------------------------
// conv20: h2 = swish(conv3d(h1, w20) + b20) * s2   (Cin=64 -> Cout=128), bf16 out
// Cross-step bb prefetch, spill-safe macros. __launch_bounds__(256,2): the
// (256,3) cap of ~168 VGPR forced the fragment arrays to scratch (r3/r4
// regression: 84 VGPR + 700MB scratch WRITE_SIZE); demand ~180 needs cap 256.
__global__ __launch_bounds__(256, 2) void conv20_kernel(
    const short* __restrict__ h1, const short* __restrict__ wt,
    const float* __restrict__ b20, const float* __restrict__ s2,
    short* __restrict__ h2) {
  __shared__ __align__(16) short sm[24704];   // inbuf 8320 + wbuf 2*8192
  const int tid = threadIdx.x;
  const int bi = blockIdx.x;
  const int xcd = bi & 7, slot = bi >> 3;
  const int yo = slot & 15, z = (slot >> 4) & 7, b = slot >> 7;
  const int y = xcd * 16 + yo;
  const int gid = b * 1024 + z * 128 + y;
  const int lane = tid & 63, wave = tid >> 6;
  const int wm = wave >> 1, wn = wave & 1;
  const int q = lane >> 4, n0 = lane & 15;
  const bf16x8 zz = {0, 0, 0, 0, 0, 0, 0, 0};
  short* inbuf = sm;                          // [130 x][64 ci], 8-unit xor swizzle
  f32x4 acc[4][4];
#pragma unroll
  for (int i = 0; i < 4; ++i)
#pragma unroll
    for (int j = 0; j < 4; ++j) acc[i][j] = (f32x4){0.f, 0.f, 0.f, 0.f};

  auto wstage = [&](int s) {                  // tap s -> wbuf[s&1]; [co 128][8 units, u^co swz]
    const short* src = wt + (s << 13);
    short* dst = sm + 8320 + ((s & 1) << 13);
    int r = lane >> 3, ss = lane & 7;
#pragma unroll
    for (int i = 0; i < 4; ++i) {
      int c = wave * 4 + i;
      gld_lds16(src + ((c * 8 + r) << 6) + ((ss ^ r) << 3), dst + (c << 9));
    }
  };
  auto instage = [&](int it) {                // row (kz,ky)=it -> inbuf rows 1..128
    int kz = it / 3, ky = it - kz * 3;
    int zi = z + kz - 1, yi = y + ky - 1;
    if (zi >= 0 && zi < 8 && yi >= 0 && yi < 128) {
      const short* row = h1 + ((size_t)(b * 1024 + zi * 128 + yi) << 13);
#pragma unroll
      for (int i = 0; i < 4; ++i) {
        int x0 = 1 + 8 * (wave * 4 + i);
        int x = x0 + (lane >> 3);
        int c8 = (lane & 7) ^ (x & 7);
        gld_lds16(row + ((x - 1) << 6) + (c8 << 3), inbuf + (x0 << 6));
      }
    } else {
#pragma unroll
      for (int i = 0; i < 4; ++i)
        *(bf16x8*)(&inbuf[64 + (i * 256 + tid) * 8]) = zz;
      asm volatile("s_waitcnt lgkmcnt(0)" ::: "memory");
    }
  };

  if (tid < 16) {                             // halo rows 0,129 zero (persist)
    int hf = tid >> 3, u = tid & 7;
    *(bf16x8*)(&inbuf[(hf ? 129 : 0) * 64 + u * 8]) = zz;
  }
  wstage(0);
  instage(0);
  __syncthreads();                            // prologue: one full drain (once)

  bf16x8 af[2][4], bbA[2][4], bbB[2][4];

#define C20_AF(PAR)                                                            \
  { const short* w_ = sm + 8320 + ((PAR) << 13);                               \
    _Pragma("unroll") for (int ch = 0; ch < 2; ++ch)                           \
    _Pragma("unroll") for (int i = 0; i < 4; ++i)                              \
      af[ch][i] = *(const bf16x8*)(&w_[(wm * 64 + i * 16 + n0) * 64 +          \
                                       (((ch * 4 + q) ^ (n0 & 7)) << 3)]); }
#define C20_BB(KX, BB)                                                         \
  { _Pragma("unroll") for (int ch = 0; ch < 2; ++ch)                           \
    _Pragma("unroll") for (int j = 0; j < 4; ++j) {                            \
      int xx = wn * 64 + j * 16 + n0 + (KX);                                   \
      BB[ch][j] = *(const bf16x8*)(&inbuf[xx * 64 +                            \
                                          (((ch * 4 + q) ^ (xx & 7)) << 3)]); } }
#define C20_MFMA(BB)                                                           \
  { __builtin_amdgcn_s_setprio(1);                                             \
    _Pragma("unroll") for (int ch = 0; ch < 2; ++ch)                           \
    _Pragma("unroll") for (int i = 0; i < 4; ++i)                              \
    _Pragma("unroll") for (int j = 0; j < 4; ++j)                              \
      acc[i][j] = __builtin_amdgcn_mfma_f32_16x16x32_bf16(af[ch][i], BB[ch][j],\
                                                          acc[i][j], 0, 0, 0); \
    __builtin_amdgcn_s_setprio(0); }

  for (int g = 0; g < 8; ++g) {               // groups of 3 steps (one (kz,ky) row)
    const int s3 = g * 3;
    wstage(s3 + 1); ACQ("4");                 // certify wstage(s3) [+instage(g)]
    C20_AF(g & 1);
    C20_BB(0, bbA);
    C20_BB(1, bbB);                           // prefetch kx=1 (hides under MFMA)
    C20_MFMA(bbA);
    REL();
    wstage(s3 + 2); ACQ("4");
    C20_AF((g & 1) ^ 1);
    C20_BB(2, bbA);                           // prefetch kx=2
    C20_MFMA(bbB);
    REL();
    wstage(s3 + 3); ACQ("4");
    C20_AF(g & 1);
    C20_MFMA(bbA);                            // no bb read: fully hidden step
    REL();
    instage(g + 1);                           // in flight; certified by next ACQ
  }
  {                                           // tail: s=24,25,26 (inbuf row 8)
    wstage(25); ACQ("4"); C20_AF(0);
    C20_BB(0, bbA); C20_BB(1, bbB);
    C20_MFMA(bbA); REL();
    wstage(26); ACQ("4"); C20_AF(1);
    C20_BB(2, bbA);
    C20_MFMA(bbB); REL();
    ACQ("0"); C20_AF(0);
    C20_MFMA(bbA); REL();
  }
#undef C20_AF
#undef C20_BB
#undef C20_MFMA
  // epilogue: bias + swish + s2, transpose through LDS, contiguous bf16 row out
#pragma unroll
  for (int i = 0; i < 4; ++i) {
    const int mb = wm * 64 + i * 16 + q * 4;
    const float4 bias = *(const float4*)(b20 + mb);
    const float4 sc = *(const float4*)(s2 + b * 128 + mb);
#pragma unroll
    for (int j = 0; j < 4; ++j) {
      const int n = wn * 64 + j * 16 + n0;
      bf16x4v pk;
      pk.x = f2bf(swish_f(acc[i][j][0] + bias.x) * sc.x);
      pk.y = f2bf(swish_f(acc[i][j][1] + bias.y) * sc.y);
      pk.z = f2bf(swish_f(acc[i][j][2] + bias.z) * sc.z);
      pk.w = f2bf(swish_f(acc[i][j][3] + bias.w) * sc.w);
      *(bf16x4v*)(&sm[n * 136 + mb]) = pk;
    }
  }
  __syncthreads();
  short* orow = h2 + (size_t)gid * 16384;
#pragma unroll
  for (int i = 0; i < 8; ++i) {               // 2048 vec8
    int e = i * 256 + tid;
    int xx = e >> 4, c8 = e & 15;
    *(bf16x8*)(orow + e * 8) = *(const bf16x8*)(&sm[xx * 136 + c8 * 8]);
  }
}

// ------------------------------------------------------------------
// conv21: h3 = swish(conv3d(h2, w21) + conv1x1(x, res_w) + res_b)  (128->128), bf16
// Cross-step bb prefetch (period-6), spill-safe macro form.
__global__ __launch_bounds__(256, 2) void conv21_kernel(
    const short* __restrict__ h2, const short* __restrict__ wt,
    const float* __restrict__ xin, const short* __restrict__ rw,
    const float* __restrict__ res_b, short* __restrict__ h3) {
  __shared__ __align__(16) short sm[33024];   // inbuf 16640 + wbuf 2*8192
  const int tid = threadIdx.x;
  const int bi = blockIdx.x;
  const int xcd = bi & 7, slot = bi >> 3;
  const int yo = slot & 15, z = (slot >> 4) & 7, b = slot >> 7;
  const int y = xcd * 16 + yo;
  const int gid = b * 1024 + z * 128 + y;
  const int lane = tid & 63, wave = tid >> 6;
  const int wm = wave >> 1, wn = wave & 1;
  const int q = lane >> 4, n0 = lane & 15;
  const bf16x8 zz = {0, 0, 0, 0, 0, 0, 0, 0};
  short* inbuf = sm;                          // [130 x][128 ci], 16-unit xor swizzle
  f32x4 acc[4][4];
#pragma unroll
  for (int i = 0; i < 4; ++i)
#pragma unroll
    for (int j = 0; j < 4; ++j) acc[i][j] = (f32x4){0.f, 0.f, 0.f, 0.f};

  auto wstage = [&](int s) {                  // half-tap s -> wbuf[s&1]; [co 128][8 units, u^co]
    int it6 = s / 6, sub = s - it6 * 6, kx = sub >> 1, ch2 = sub & 1;
    const short* src = wt + (((it6 * 3 + kx) << 14) + (ch2 << 6));
    short* dst = sm + 16640 + ((s & 1) << 13);
    int r = lane >> 3, ss = lane & 7;
#pragma unroll
    for (int i = 0; i < 4; ++i) {
      int c = wave * 4 + i;
      gld_lds16(src + ((c * 8 + r) << 7) + ((ss ^ r) << 3), dst + (c << 9));
    }
  };
  auto instage = [&](int it) {
    int kz = it / 3, ky = it - kz * 3;
    int zi = z + kz - 1, yi = y + ky - 1;
    if (zi >= 0 && zi < 8 && yi >= 0 && yi < 128) {
      const short* row = h2 + ((size_t)(b * 1024 + zi * 128 + yi) << 14);
#pragma unroll
      for (int i = 0; i < 8; ++i) {
        int x0 = 1 + 4 * (wave * 8 + i);
        int x = x0 + (lane >> 4);
        int c8 = (lane & 15) ^ (x & 15);
        gld_lds16(row + ((x - 1) << 7) + (c8 << 3), inbuf + (x0 << 7));
      }
    } else {
#pragma unroll
      for (int i = 0; i < 8; ++i)
        *(bf16x8*)(&inbuf[128 + (i * 256 + tid) * 8]) = zz;
      asm volatile("s_waitcnt lgkmcnt(0)" ::: "memory");
    }
  };

  if (tid < 32) {                             // halo rows 0,129 zero (persist)
    int hf = tid >> 4, u = tid & 15;
    *(bf16x8*)(&inbuf[(hf ? 129 : 0) * 128 + u * 8]) = zz;
  }
  wstage(0);
  instage(0);
  __syncthreads();                            // prologue: one full drain (once)

  bf16x8 af[2][4], bbA[2][4], bbB[2][4];
  float4 xv[8];

#define C21_AF(PAR)                                                            \
  { const short* w_ = sm + 16640 + ((PAR) << 13);                              \
    _Pragma("unroll") for (int chL = 0; chL < 2; ++chL)                        \
    _Pragma("unroll") for (int i = 0; i < 4; ++i)                              \
      af[chL][i] = *(const bf16x8*)(&w_[(wm * 64 + i * 16 + n0) * 64 +         \
                                        (((chL * 4 + q) ^ (n0 & 7)) << 3)]); }
#define C21_BB(KX, CH2, BB)                                                    \
  { _Pragma("unroll") for (int chL = 0; chL < 2; ++chL) {                      \
      const int ch = (CH2) * 2 + chL;                                          \
      _Pragma("unroll") for (int j = 0; j < 4; ++j) {                          \
        int xx = wn * 64 + j * 16 + n0 + (KX);                                 \
        BB[chL][j] = *(const bf16x8*)(&inbuf[(xx << 7) +                       \
                                      (((ch * 4 + q) ^ (xx & 15)) << 3)]); } } }
#define C21_MFMA(BB)                                                           \
  { __builtin_amdgcn_s_setprio(1);                                             \
    _Pragma("unroll") for (int chL = 0; chL < 2; ++chL)                        \
    _Pragma("unroll") for (int i = 0; i < 4; ++i)                              \
    _Pragma("unroll") for (int j = 0; j < 4; ++j)                              \
      acc[i][j] = __builtin_amdgcn_mfma_f32_16x16x32_bf16(af[chL][i], BB[chL][j],\
                                                          acc[i][j], 0, 0, 0); \
    __builtin_amdgcn_s_setprio(0); }

  for (int g = 0; g < 8; ++g) {               // groups of 6 steps (one (kz,ky) row)
    const int s6 = g * 6;
    wstage(s6 + 1); ACQ("4");                 // certify wstage(s6) [+instage(g)]
    C21_AF(0);
    C21_BB(0, 0, bbA);
    C21_BB(0, 1, bbB);                        // prefetch (kx0,ch1)
    C21_MFMA(bbA); REL();
    wstage(s6 + 2); ACQ("4"); C21_AF(1);
    C21_BB(1, 0, bbA);                        // prefetch (kx1,ch0)
    C21_MFMA(bbB); REL();
    wstage(s6 + 3); ACQ("4"); C21_AF(0);
    C21_BB(1, 1, bbB);                        // prefetch (kx1,ch1)
    C21_MFMA(bbA); REL();
    wstage(s6 + 4); ACQ("4"); C21_AF(1);
    C21_BB(2, 0, bbA);                        // prefetch (kx2,ch0)
    C21_MFMA(bbB); REL();
    wstage(s6 + 5); ACQ("4"); C21_AF(0);
    C21_BB(2, 1, bbB);                        // prefetch (kx2,ch1)
    C21_MFMA(bbA); REL();
    wstage(s6 + 6); ACQ("4"); C21_AF(1);
    C21_MFMA(bbB); REL();                     // no bb read
    instage(g + 1);
  }
  {                                           // tail: s=48..53 (inbuf row 8)
    wstage(49); ACQ("4"); C21_AF(0);
    C21_BB(0, 0, bbA); C21_BB(0, 1, bbB);
    C21_MFMA(bbA); REL();
    wstage(50); ACQ("4"); C21_AF(1);
    C21_BB(1, 0, bbA);
    C21_MFMA(bbB); REL();
    wstage(51); ACQ("4"); C21_AF(0);
    C21_BB(1, 1, bbB);
    C21_MFMA(bbA); REL();
    wstage(52); ACQ("4");
    {                                         // prefetch fp32 res row to regs
      const float* xb = xin + (size_t)b * 8388608 + (size_t)z * 16384 + (size_t)y * 128;
#pragma unroll
      for (int i = 0; i < 8; ++i) {
        int e = i * 256 + tid;
        int ci = e >> 5, x4 = e & 31;
        xv[i] = *(const float4*)(xb + (size_t)ci * 131072 + x4 * 4);
      }
    }
    C21_AF(1);
    C21_BB(2, 0, bbA);
    C21_MFMA(bbB); REL();
    wstage(53); ACQ("12");                    // certify w52; xv(8)+w53(4) in flight
    C21_AF(0);
    C21_BB(2, 1, bbB);
    C21_MFMA(bbA); REL();
    ACQ("0");                                 // certify w53 (drains xv too)
    C21_AF(1);
    C21_MFMA(bbB); REL();
  }
#undef C21_AF
#undef C21_BB
#undef C21_MFMA
  // res 1x1 tap: write x row (bf16, 64-ci swizzle incl. (xx>>3) bit) into free wbuf
  short* rbuf = sm + 16640;                   // s=53 read parity 1; buf 0 free
  {
#pragma unroll
    for (int i = 0; i < 8; ++i) {
      int e = i * 256 + tid;
      int ci = e >> 5, x4 = e & 31;
      int u0 = ci >> 3, cl = ci & 7;
#pragma unroll
      for (int k = 0; k < 4; ++k) {
        int xx = x4 * 4 + k;
        float fv = (k == 0) ? xv[i].x : (k == 1) ? xv[i].y : (k == 2) ? xv[i].z : xv[i].w;
        rbuf[xx * 64 + ((u0 ^ (xx & 7) ^ ((xx >> 3) & 7)) << 3) + cl] = f2bf(fv);
      }
    }
  }
  __syncthreads();
#pragma unroll
  for (int ch = 0; ch < 2; ++ch) {
    bf16x8 raf[4], rbb[4];
#pragma unroll
    for (int i = 0; i < 4; ++i)
      raf[i] = *(const bf16x8*)(rw + (wm * 64 + i * 16 + n0) * 64 + ch * 32 + q * 8);
#pragma unroll
    for (int j = 0; j < 4; ++j) {
      int xx = wn * 64 + j * 16 + n0;
      rbb[j] = *(const bf16x8*)(&rbuf[xx * 64 + (((ch * 4 + q) ^ (xx & 7) ^ ((xx >> 3) & 7)) << 3)]);
    }
#pragma unroll
    for (int i = 0; i < 4; ++i)
#pragma unroll
      for (int j = 0; j < 4; ++j)
        acc[i][j] = __builtin_amdgcn_mfma_f32_16x16x32_bf16(raf[i], rbb[j], acc[i][j], 0, 0, 0);
  }
  __syncthreads();
  // epilogue: + res_b, swish, bf16 out (channels-last)
#pragma unroll
  for (int i = 0; i < 4; ++i) {
    const int mb = wm * 64 + i * 16 + q * 4;
    const float4 bias = *(const float4*)(res_b + mb);
#pragma unroll
    for (int j = 0; j < 4; ++j) {
      const int n = wn * 64 + j * 16 + n0;
      bf16x4v pk;
      pk.x = f2bf(swish_f(acc[i][j][0] + bias.x));
      pk.y = f2bf(swish_f(acc[i][j][1] + bias.y));
      pk.z = f2bf(swish_f(acc[i][j][2] + bias.z));
      pk.w = f2bf(swish_f(acc[i][j][3] + bias.w));
      *(bf16x4v*)(&sm[n * 136 + mb]) = pk;
    }
  }
  __syncthreads();
  short* orow = h3 + (size_t)gid * 16384;
#pragma unroll
  for (int i = 0; i < 8; ++i) {
    int e = i * 256 + tid;
    int xx = e >> 4, c8 = e & 15;
    *(bf16x8*)(orow + e * 8) = *(const bf16x8*)(&sm[xx * 136 + c8 * 8]);
  }
}

// ------------------------------------------------------------------
// down: out = conv3d(h3, down_w, stride (1,2,2), pad z only) + down_b, fp32 NCDHW
__global__ __launch_bounds__(256, 2) void down_kernel(
    const short* __restrict__ h3, const short* __restrict__ wt,
    const float* __restrict__ dnb, float* __restrict__ out) {
  __shared__ __align__(16) short sm[33024];   // inbuf 16640 + wbuf 2*8192
  const int tid = threadIdx.x;
  const int bi = blockIdx.x;                  // 4*8*63 = 2016
  const int o = (bi & 7) * 252 + (bi >> 3);
  const int yo = o % 63;
  const int zb = o / 63;
  const int z = zb & 7, b = zb >> 3;
  const int lane = tid & 63, wave = tid >> 6;
  const int wm = wave >> 1, wn = wave & 1;
  const int q = lane >> 4, n0 = lane & 15;
  const bf16x8 zz = {0, 0, 0, 0, 0, 0, 0, 0};
  short* inbuf = sm;                          // [130 x][128 ci], rows 0..127 data
  f32x4 acc[4][2];
#pragma unroll
  for (int i = 0; i < 4; ++i)
#pragma unroll
    for (int j = 0; j < 2; ++j) acc[i][j] = (f32x4){0.f, 0.f, 0.f, 0.f};

  auto wstage = [&](int s) {
    int it6 = s / 6, sub = s - it6 * 6, kx = sub >> 1, ch2 = sub & 1;
    const short* src = wt + (((it6 * 3 + kx) << 14) + (ch2 << 6));
    short* dst = sm + 16640 + ((s & 1) << 13);
    int r = lane >> 3, ss = lane & 7;
#pragma unroll
    for (int i = 0; i < 4; ++i) {
      int c = wave * 4 + i;
      gld_lds16(src + ((c * 8 + r) << 7) + ((ss ^ r) << 3), dst + (c << 9));
    }
  };
  auto instage = [&](int it) {
    int kz = it / 3, ky = it - kz * 3;
    int zi = z + kz - 1;
    int yi = 2 * yo + ky;                     // always in range
    if (zi >= 0 && zi < 8) {
      const short* row = h3 + ((size_t)(b * 1024 + zi * 128 + yi) << 14);
#pragma unroll
      for (int i = 0; i < 8; ++i) {
        int x0 = 4 * (wave * 8 + i);          // no x shift
        int x = x0 + (lane >> 4);
        int c8 = (lane & 15) ^ (x & 15);
        gld_lds16(row + (x << 7) + (c8 << 3), inbuf + (x0 << 7));
      }
    } else {
#pragma unroll
      for (int i = 0; i < 8; ++i)
        *(bf16x8*)(&inbuf[(i * 256 + tid) * 8]) = zz;
      asm volatile("s_waitcnt lgkmcnt(0)" ::: "memory");
    }
  };

  if (tid < 32) {                             // rows 128,129 zero (dead n=63 lanes)
    int hf = tid >> 4, u = tid & 15;
    *(bf16x8*)(&inbuf[(128 + hf) * 128 + u * 8]) = zz;
  }
  wstage(0);
  instage(0);
  __syncthreads();                            // prologue: one full drain (once)

  bf16x8 af[2][4], bbA[2][2], bbB[2][2];

#define DN_AF(PAR)                                                             \
  { const short* w_ = sm + 16640 + ((PAR) << 13);                              \
    _Pragma("unroll") for (int chL = 0; chL < 2; ++chL)                        \
    _Pragma("unroll") for (int i = 0; i < 4; ++i)                              \
      af[chL][i] = *(const bf16x8*)(&w_[(wm * 64 + i * 16 + n0) * 64 +         \
                                        (((chL * 4 + q) ^ (n0 & 7)) << 3)]); }
#define DN_BB(KX, CH2, BB)                                                     \
  { _Pragma("unroll") for (int chL = 0; chL < 2; ++chL) {                      \
      const int ch = (CH2) * 2 + chL;                                          \
      _Pragma("unroll") for (int j = 0; j < 2; ++j) {                          \
        int xp = 2 * (wn * 32 + j * 16 + n0) + (KX);                           \
        BB[chL][j] = *(const bf16x8*)(&inbuf[(xp << 7) +                       \
                                      (((ch * 4 + q) ^ (xp & 15)) << 3)]); } } }
#define DN_MFMA(BB)                                                            \
  { __builtin_amdgcn_s_setprio(1);                                             \
    _Pragma("unroll") for (int chL = 0; chL < 2; ++chL)                        \
    _Pragma("unroll") for (int i = 0; i < 4; ++i)                              \
    _Pragma("unroll") for (int j = 0; j < 2; ++j)                              \
      acc[i][j] = __builtin_amdgcn_mfma_f32_16x16x32_bf16(af[chL][i], BB[chL][j],\
                                                          acc[i][j], 0, 0, 0); \
    __builtin_amdgcn_s_setprio(0); }

  for (int g = 0; g < 8; ++g) {
    const int s6 = g * 6;
    wstage(s6 + 1); ACQ("4"); DN_AF(0);
    DN_BB(0, 0, bbA);
    DN_BB(0, 1, bbB);
    DN_MFMA(bbA); REL();
    wstage(s6 + 2); ACQ("4"); DN_AF(1);
    DN_BB(1, 0, bbA);
    DN_MFMA(bbB); REL();
    wstage(s6 + 3); ACQ("4"); DN_AF(0);
    DN_BB(1, 1, bbB);
    DN_MFMA(bbA); REL();
    wstage(s6 + 4); ACQ("4"); DN_AF(1);
    DN_BB(2, 0, bbA);
    DN_MFMA(bbB); REL();
    wstage(s6 + 5); ACQ("4"); DN_AF(0);
    DN_BB(2, 1, bbB);
    DN_MFMA(bbA); REL();
    wstage(s6 + 6); ACQ("4"); DN_AF(1);
    DN_MFMA(bbB); REL();
    instage(g + 1);
  }
  {                                           // tail: s=48..53
    wstage(49); ACQ("4"); DN_AF(0);
    DN_BB(0, 0, bbA); DN_BB(0, 1, bbB);
    DN_MFMA(bbA); REL();
    wstage(50); ACQ("4"); DN_AF(1);
    DN_BB(1, 0, bbA);
    DN_MFMA(bbB); REL();
    wstage(51); ACQ("4"); DN_AF(0);
    DN_BB(1, 1, bbB);
    DN_MFMA(bbA); REL();
    wstage(52); ACQ("4"); DN_AF(1);
    DN_BB(2, 0, bbA);
    DN_MFMA(bbB); REL();
    wstage(53); ACQ("4"); DN_AF(0);
    DN_BB(2, 1, bbB);
    DN_MFMA(bbA); REL();
    ACQ("0"); DN_AF(1);
    DN_MFMA(bbB); REL();
  }
#undef DN_AF
#undef DN_BB
#undef DN_MFMA
  // epilogue: + down_b, fp32 transpose in LDS (stride 133: conflict-free), NCDHW out
  float* fsm = (float*)sm;
#pragma unroll
  for (int i = 0; i < 4; ++i) {
    const int mb = wm * 64 + i * 16 + q * 4;
    const float4 bias = *(const float4*)(dnb + mb);
#pragma unroll
    for (int j = 0; j < 2; ++j) {
      const int n = wn * 32 + j * 16 + n0;
      f32x4 v;
      v[0] = acc[i][j][0] + bias.x;
      v[1] = acc[i][j][1] + bias.y;
      v[2] = acc[i][j][2] + bias.z;
      v[3] = acc[i][j][3] + bias.w;
      *(f32x4*)(&fsm[n * 133 + mb]) = v;
    }
  }
  __syncthreads();
#pragma unroll
  for (int it = 0; it < 32; ++it) {           // 128 co x 64 lanes (63 valid)
    int idx = it * 256 + tid;
    int co = idx >> 6, xl = idx & 63;
    if (xl < 63)
      out[((size_t)(b * 128 + co) * 8 + z) * 3969 + yo * 63 + xl] = fsm[xl * 133 + co];
  }
}

// ------------------------------------------------------------------
extern "C" void kernel_launch(void* const* d_in, const int* in_sizes, int n_in,
                              void* d_out, int out_size, void* d_ws, size_t ws_size,
                              hipStream_t stream) {
  const float* x       = (const float*)d_in[0];
  const float* embed   = (const float*)d_in[1];
  const float* context = (const float*)d_in[2];
  const float* w20     = (const float*)d_in[3];
  const float* b20     = (const float*)d_in[4];
  const float* w21     = (const float*)d_in[5];
  const float* d1w     = (const float*)d_in[6];
  const float* d1b     = (const float*)d_in[7];
  const float* d2w     = (const float*)d_in[8];
  const float* d2b     = (const float*)d_in[9];
  const float* resw    = (const float*)d_in[10];
  const float* resb    = (const float*)d_in[11];
  const float* dnw     = (const float*)d_in[12];
  const float* dnb     = (const float*)d_in[13];
  float* out = (float*)d_out;
  char* ws = (char*)d_ws;
  float* s1   = (float*)(ws + 0);          // 1 KB
  float* s2   = (float*)(ws + 1024);       // 2 KB
  short* wt20 = (short*)(ws + 4096);       // 432 KB
  short* wt21 = (short*)(ws + 446464);     // 864 KB
  short* wtdn = (short*)(ws + 1331200);    // 864 KB
  short* rw   = (short*)(ws + 2215936);    // 16 KB
  short* h1   = (short*)(ws + 2232320);    // 64 MB  [b][z][y][x][ci=64] bf16
  short* h2   = (short*)(ws + 69341184);   // 128 MB [b][z][y][x][ci=128] bf16
  short* h3   = (short*)(ws + 203558912);  // 128 MB [b][z][y][x][ci=128] bf16

  scales_kernel<<<3, 256, 0, stream>>>(embed, context, d1w, d1b, d2w, d2b, s1, s2);
  prep_w_kernel<<<1088, 256, 0, stream>>>(w20, w21, dnw, resw, wt20, wt21, wtdn, rw);
  prep_h1_kernel<<<4096, 256, 0, stream>>>(x, s1, h1);
  conv20_kernel<<<4096, 256, 0, stream>>>(h1, wt20, b20, s2, h2);
  conv21_kernel<<<4096, 256, 0, stream>>>(h2, wt21, x, rw, resb, h3);
  down_kernel<<<2016, 256, 0, stream>>>(h3, wtdn, dnb, out);
}